// Round 1
// baseline (706.261 us; speedup 1.0000x reference)
//
#include <hip/hip_runtime.h>
#include <hip/hip_bf16.h>

#define N_NODES 50000
#define E_EDGES 800000
#define NCLS 10

// ---------- helpers ----------
__device__ __forceinline__ float wsum64(float v) {
    v += __shfl_xor(v, 32, 64);
    v += __shfl_xor(v, 16, 64);
    v += __shfl_xor(v, 8, 64);
    v += __shfl_xor(v, 4, 64);
    v += __shfl_xor(v, 2, 64);
    v += __shfl_xor(v, 1, 64);
    return v;
}

// ---------- CSR build ----------
__global__ void k_count(const int* __restrict__ dst, int* __restrict__ deg) {
    int i = blockIdx.x * blockDim.x + threadIdx.x;
    if (i < E_EDGES) {
        unsigned d = (unsigned)dst[i];
        if (d < N_NODES) atomicAdd(&deg[d], 1);
    }
}

// single block, 1024 threads: exclusive scan of deg -> rowptr, cursor init in-place
__global__ void k_scan(int* __restrict__ degcur, int* __restrict__ rowptr) {
    __shared__ int sums[1024];
    const int CH = 49;  // 1024*49 >= 50000
    int t = threadIdx.x;
    int beg = t * CH;
    int end = min(beg + CH, N_NODES);
    int s = 0;
    for (int i = beg; i < end; ++i) s += degcur[i];
    sums[t] = s;
    __syncthreads();
    for (int off = 1; off < 1024; off <<= 1) {
        int v = (t >= off) ? sums[t - off] : 0;
        __syncthreads();
        sums[t] += v;
        __syncthreads();
    }
    int run = (t == 0) ? 0 : sums[t - 1];
    for (int i = beg; i < end; ++i) {
        int d = degcur[i];
        rowptr[i] = run;
        degcur[i] = run;  // cursor init
        run += d;
    }
    if (t == 1023) rowptr[N_NODES] = sums[1023];
}

__global__ void k_scatter(const int* __restrict__ src, const int* __restrict__ dst,
                          int* __restrict__ cursor, int* __restrict__ csr_src) {
    int i = blockIdx.x * blockDim.x + threadIdx.x;
    if (i < E_EDGES) {
        unsigned d = (unsigned)dst[i];
        if (d < N_NODES) {
            int p = atomicAdd(&cursor[d], 1);
            unsigned s = (unsigned)src[i];
            csr_src[p] = (s < N_NODES) ? (int)s : 0;
        }
    }
}

// ---------- fp32 GEMM: Y[n][o] = sum_k X[n][k]*W[o][k] + b[o], K=128 ----------
template <int NOUT>
__global__ __launch_bounds__(256) void k_gemm(const float* __restrict__ X,
                                              const float* __restrict__ W,
                                              const float* __restrict__ b,
                                              float* __restrict__ Y, int nrows) {
    const int K = 128;
    __shared__ float Xs[64][33];
    __shared__ float Ws[32][NOUT + 1];
    const int CN = NOUT / 16;  // cols per thread (8 or 4)
    int row0 = blockIdx.x * 64;
    int tr = threadIdx.x >> 4;   // 0..15
    int tc = threadIdx.x & 15;   // 0..15
    float acc[4][CN] = {};
    for (int k0 = 0; k0 < K; k0 += 32) {
        for (int idx = threadIdx.x; idx < 64 * 32; idx += 256) {
            int r = idx >> 5, k = idx & 31;
            int gr = row0 + r;
            Xs[r][k] = (gr < nrows) ? X[(size_t)gr * K + k0 + k] : 0.f;
        }
        for (int idx = threadIdx.x; idx < NOUT * 32; idx += 256) {
            int o = idx >> 5, k = idx & 31;
            Ws[k][o] = W[(size_t)o * K + k0 + k];
        }
        __syncthreads();
#pragma unroll
        for (int kk = 0; kk < 32; ++kk) {
            float xv[4];
#pragma unroll
            for (int i = 0; i < 4; ++i) xv[i] = Xs[tr * 4 + i][kk];
#pragma unroll
            for (int j = 0; j < CN; ++j) {
                float wv = Ws[kk][j * 16 + tc];
#pragma unroll
                for (int i = 0; i < 4; ++i) acc[i][j] = fmaf(xv[i], wv, acc[i][j]);
            }
        }
        __syncthreads();
    }
#pragma unroll
    for (int i = 0; i < 4; ++i) {
        int gr = row0 + tr * 4 + i;
        if (gr >= nrows) continue;
#pragma unroll
        for (int j = 0; j < CN; ++j) {
            int o = j * 16 + tc;
            Y[(size_t)gr * NOUT + o] = acc[i][j] + b[o];
        }
    }
}

// ---------- GATv2 layer 1: H=2, C=64, concat -> out[N][128], fused bias+ELU ----------
__global__ __launch_bounds__(256) void k_gat1(const float* __restrict__ xl,
                                              const float* __restrict__ xr,
                                              const int* __restrict__ rowptr,
                                              const int* __restrict__ csr,
                                              const float* __restrict__ att,
                                              const float* __restrict__ bias,
                                              float* __restrict__ out) {
    int node = blockIdx.x * 4 + (threadIdx.x >> 6);
    if (node >= N_NODES) return;
    int lane = threadIdx.x & 63;
    float a0 = att[lane], a1 = att[64 + lane];
    size_t nb = (size_t)node * 128;
    float xr0 = xr[nb + lane], xr1 = xr[nb + 64 + lane];
    // self loop
    float sl0 = xl[nb + lane], sl1 = xl[nb + 64 + lane];
    float t0 = sl0 + xr0; t0 = t0 > 0.f ? t0 : 0.2f * t0;
    float t1 = sl1 + xr1; t1 = t1 > 0.f ? t1 : 0.2f * t1;
    float s0 = wsum64(t0 * a0);
    float s1 = wsum64(t1 * a1);
    float w0 = __expf(s0), w1 = __expf(s1);
    float den0 = w0, den1 = w1;
    float acc0 = w0 * sl0, acc1 = w1 * sl1;
    int beg = rowptr[node], end = rowptr[node + 1];
    if (beg < end) {
        int s = csr[beg];
        float v0 = xl[(size_t)s * 128 + lane], v1 = xl[(size_t)s * 128 + 64 + lane];
        for (int e = beg + 1; e <= end; ++e) {
            float nv0 = 0.f, nv1 = 0.f;
            if (e < end) {
                int ns = csr[e];
                nv0 = xl[(size_t)ns * 128 + lane];
                nv1 = xl[(size_t)ns * 128 + 64 + lane];
            }
            float u0 = v0 + xr0; u0 = u0 > 0.f ? u0 : 0.2f * u0;
            float u1 = v1 + xr1; u1 = u1 > 0.f ? u1 : 0.2f * u1;
            float sc0 = wsum64(u0 * a0);
            float sc1 = wsum64(u1 * a1);
            float e0 = __expf(sc0), e1 = __expf(sc1);
            den0 += e0; den1 += e1;
            acc0 = fmaf(e0, v0, acc0);
            acc1 = fmaf(e1, v1, acc1);
            v0 = nv0; v1 = nv1;
        }
    }
    float o0 = acc0 / den0 + bias[lane];
    float o1 = acc1 / den1 + bias[64 + lane];
    o0 = o0 > 0.f ? o0 : expm1f(o0);
    o1 = o1 > 0.f ? o1 : expm1f(o1);
    out[nb + lane] = o0;
    out[nb + 64 + lane] = o1;
}

// ---------- GATv2 layer 2: H=1, C=64 -> out[N][64], fused bias+ELU ----------
__global__ __launch_bounds__(256) void k_gat2(const float* __restrict__ xl,
                                              const float* __restrict__ xr,
                                              const int* __restrict__ rowptr,
                                              const int* __restrict__ csr,
                                              const float* __restrict__ att,
                                              const float* __restrict__ bias,
                                              float* __restrict__ out) {
    int node = blockIdx.x * 4 + (threadIdx.x >> 6);
    if (node >= N_NODES) return;
    int lane = threadIdx.x & 63;
    float a = att[lane];
    size_t nb = (size_t)node * 64;
    float xrv = xr[nb + lane];
    float slv = xl[nb + lane];
    float t = slv + xrv; t = t > 0.f ? t : 0.2f * t;
    float s = wsum64(t * a);
    float w = __expf(s);
    float den = w;
    float acc = w * slv;
    int beg = rowptr[node], end = rowptr[node + 1];
    if (beg < end) {
        int sidx = csr[beg];
        float v = xl[(size_t)sidx * 64 + lane];
        for (int e = beg + 1; e <= end; ++e) {
            float nv = 0.f;
            if (e < end) {
                int ns = csr[e];
                nv = xl[(size_t)ns * 64 + lane];
            }
            float u = v + xrv; u = u > 0.f ? u : 0.2f * u;
            float sc = wsum64(u * a);
            float ee = __expf(sc);
            den += ee;
            acc = fmaf(ee, v, acc);
            v = nv;
        }
    }
    float o = acc / den + bias[lane];
    out[nb + lane] = o > 0.f ? o : expm1f(o);
}

// ---------- classifier head: logits[n][10] = h[n][:64] @ Wc^T + bc ----------
__global__ __launch_bounds__(256) void k_head(const float* __restrict__ H,
                                              const float* __restrict__ Wc,
                                              const float* __restrict__ bc,
                                              float* __restrict__ out) {
    __shared__ float Ws[NCLS * 64];
    __shared__ float bs[NCLS];
    for (int i = threadIdx.x; i < NCLS * 64; i += 256) Ws[i] = Wc[i];
    if (threadIdx.x < NCLS) bs[threadIdx.x] = bc[threadIdx.x];
    __syncthreads();
    int n = blockIdx.x * 256 + threadIdx.x;
    if (n >= N_NODES) return;
    const float4* hp = (const float4*)(H + (size_t)n * 64);
    float acc[NCLS] = {};
#pragma unroll
    for (int k4 = 0; k4 < 16; ++k4) {
        float4 hv = hp[k4];
#pragma unroll
        for (int c = 0; c < NCLS; ++c) {
            acc[c] = fmaf(hv.x, Ws[c * 64 + k4 * 4 + 0], acc[c]);
            acc[c] = fmaf(hv.y, Ws[c * 64 + k4 * 4 + 1], acc[c]);
            acc[c] = fmaf(hv.z, Ws[c * 64 + k4 * 4 + 2], acc[c]);
            acc[c] = fmaf(hv.w, Ws[c * 64 + k4 * 4 + 3], acc[c]);
        }
    }
#pragma unroll
    for (int c = 0; c < NCLS; ++c) out[(size_t)n * NCLS + c] = acc[c] + bs[c];
}

// ---------- launch ----------
extern "C" void kernel_launch(void* const* d_in, const int* in_sizes, int n_in,
                              void* d_out, int out_size, void* d_ws, size_t ws_size,
                              hipStream_t stream) {
    const float* x     = (const float*)d_in[0];
    const int*   ei    = (const int*)d_in[1];
    const int*   srcp  = ei;
    const int*   dstp  = ei + E_EDGES;
    const float* Wl1   = (const float*)d_in[3];
    const float* bl1   = (const float*)d_in[4];
    const float* Wr1   = (const float*)d_in[5];
    const float* br1   = (const float*)d_in[6];
    const float* att1  = (const float*)d_in[7];
    const float* bias1 = (const float*)d_in[8];
    const float* Wl2   = (const float*)d_in[9];
    const float* bl2   = (const float*)d_in[10];
    const float* Wr2   = (const float*)d_in[11];
    const float* br2   = (const float*)d_in[12];
    const float* att2  = (const float*)d_in[13];
    const float* bias2 = (const float*)d_in[14];
    const float* Wc    = (const float*)d_in[15];
    const float* bc    = (const float*)d_in[16];

    float* fA = (float*)d_ws;                       // xl1 [N,128] -> xl2 [N,64]
    float* fB = fA + (size_t)N_NODES * 128;         // xr1 [N,128] -> xr2 [N,64]
    float* fC = fB + (size_t)N_NODES * 128;         // h1  [N,128] -> h2  [N,64]
    int* rowptr = (int*)(fC + (size_t)N_NODES * 128);
    int* degcur = rowptr + (N_NODES + 1);
    int* csr    = degcur + N_NODES;

    hipMemsetAsync(degcur, 0, N_NODES * sizeof(int), stream);
    k_count<<<(E_EDGES + 255) / 256, 256, 0, stream>>>(dstp, degcur);
    k_scan<<<1, 1024, 0, stream>>>(degcur, rowptr);
    k_scatter<<<(E_EDGES + 255) / 256, 256, 0, stream>>>(srcp, dstp, degcur, csr);

    int gblocks = (N_NODES + 63) / 64;
    k_gemm<128><<<gblocks, 256, 0, stream>>>(x, Wl1, bl1, fA, N_NODES);
    k_gemm<128><<<gblocks, 256, 0, stream>>>(x, Wr1, br1, fB, N_NODES);
    k_gat1<<<(N_NODES + 3) / 4, 256, 0, stream>>>(fA, fB, rowptr, csr, att1, bias1, fC);
    k_gemm<64><<<gblocks, 256, 0, stream>>>(fC, Wl2, bl2, fA, N_NODES);
    k_gemm<64><<<gblocks, 256, 0, stream>>>(fC, Wr2, br2, fB, N_NODES);
    k_gat2<<<(N_NODES + 3) / 4, 256, 0, stream>>>(fA, fB, rowptr, csr, att2, bias2, fC);
    k_head<<<(N_NODES + 255) / 256, 256, 0, stream>>>(fC, Wc, bc, (float*)d_out);
}

// Round 3
// 622.053 us; speedup vs baseline: 1.1354x; 1.1354x over previous
//
#include <hip/hip_runtime.h>
#include <hip/hip_bf16.h>

#define N_NODES 50000
#define E_EDGES 800000
#define NCLS 10

// ---------- DPP wave-64 sum reduction ----------
// row_shr:1/2/4/8 build per-16-lane-row inclusive sums; row_bcast15 (rows 1,3)
// and row_bcast31 (rows 2,3) combine rows; total lands in lane 63.
template <int CTRL, int RM>
__device__ __forceinline__ float dppadd(float x) {
    int s = __builtin_amdgcn_update_dpp(0, __float_as_int(x), CTRL, RM, 0xf, true);
    return x + __int_as_float(s);
}
__device__ __forceinline__ float rl63(float x) {
    return __int_as_float(__builtin_amdgcn_readlane(__float_as_int(x), 63));
}
__device__ __forceinline__ void dred1(float& x0) {
    x0 = dppadd<0x111, 0xf>(x0);
    x0 = dppadd<0x112, 0xf>(x0);
    x0 = dppadd<0x114, 0xf>(x0);
    x0 = dppadd<0x118, 0xf>(x0);
    x0 = dppadd<0x142, 0xa>(x0);
    x0 = dppadd<0x143, 0xc>(x0);
}
__device__ __forceinline__ void dred2(float& x0, float& x1) {
    x0 = dppadd<0x111, 0xf>(x0); x1 = dppadd<0x111, 0xf>(x1);
    x0 = dppadd<0x112, 0xf>(x0); x1 = dppadd<0x112, 0xf>(x1);
    x0 = dppadd<0x114, 0xf>(x0); x1 = dppadd<0x114, 0xf>(x1);
    x0 = dppadd<0x118, 0xf>(x0); x1 = dppadd<0x118, 0xf>(x1);
    x0 = dppadd<0x142, 0xa>(x0); x1 = dppadd<0x142, 0xa>(x1);
    x0 = dppadd<0x143, 0xc>(x0); x1 = dppadd<0x143, 0xc>(x1);
}
__device__ __forceinline__ void dred4(float& x0, float& x1, float& x2, float& x3) {
    x0 = dppadd<0x111, 0xf>(x0); x1 = dppadd<0x111, 0xf>(x1);
    x2 = dppadd<0x111, 0xf>(x2); x3 = dppadd<0x111, 0xf>(x3);
    x0 = dppadd<0x112, 0xf>(x0); x1 = dppadd<0x112, 0xf>(x1);
    x2 = dppadd<0x112, 0xf>(x2); x3 = dppadd<0x112, 0xf>(x3);
    x0 = dppadd<0x114, 0xf>(x0); x1 = dppadd<0x114, 0xf>(x1);
    x2 = dppadd<0x114, 0xf>(x2); x3 = dppadd<0x114, 0xf>(x3);
    x0 = dppadd<0x118, 0xf>(x0); x1 = dppadd<0x118, 0xf>(x1);
    x2 = dppadd<0x118, 0xf>(x2); x3 = dppadd<0x118, 0xf>(x3);
    x0 = dppadd<0x142, 0xa>(x0); x1 = dppadd<0x142, 0xa>(x1);
    x2 = dppadd<0x142, 0xa>(x2); x3 = dppadd<0x142, 0xa>(x3);
    x0 = dppadd<0x143, 0xc>(x0); x1 = dppadd<0x143, 0xc>(x1);
    x2 = dppadd<0x143, 0xc>(x2); x3 = dppadd<0x143, 0xc>(x3);
}
__device__ __forceinline__ float lrelu(float u) { return u > 0.f ? u : 0.2f * u; }

// ---------- CSR build ----------
__global__ void k_count(const int* __restrict__ dst, int* __restrict__ deg) {
    int i = blockIdx.x * blockDim.x + threadIdx.x;
    if (i < E_EDGES) {
        unsigned d = (unsigned)dst[i];
        if (d < N_NODES) atomicAdd(&deg[d], 1);
    }
}

__global__ void k_scan(int* __restrict__ degcur, int* __restrict__ rowptr) {
    __shared__ int sums[1024];
    const int CH = 49;
    int t = threadIdx.x;
    int beg = t * CH;
    int end = min(beg + CH, N_NODES);
    int s = 0;
    for (int i = beg; i < end; ++i) s += degcur[i];
    sums[t] = s;
    __syncthreads();
    for (int off = 1; off < 1024; off <<= 1) {
        int v = (t >= off) ? sums[t - off] : 0;
        __syncthreads();
        sums[t] += v;
        __syncthreads();
    }
    int run = (t == 0) ? 0 : sums[t - 1];
    for (int i = beg; i < end; ++i) {
        int d = degcur[i];
        rowptr[i] = run;
        degcur[i] = run;
        run += d;
    }
    if (t == 1023) rowptr[N_NODES] = sums[1023];
}

__global__ void k_scatter(const int* __restrict__ src, const int* __restrict__ dst,
                          int* __restrict__ cursor, int* __restrict__ csr_src) {
    int i = blockIdx.x * blockDim.x + threadIdx.x;
    if (i < E_EDGES) {
        unsigned d = (unsigned)dst[i];
        if (d < N_NODES) {
            int p = atomicAdd(&cursor[d], 1);
            unsigned s = (unsigned)src[i];
            csr_src[p] = (s < N_NODES) ? (int)s : 0;
        }
    }
}

// ---------- fused dual GEMM: Yl = X@Wl^T+bl, Yr = X@Wr^T+br, K=128 ----------
template <int NOUT>
__global__ __launch_bounds__(256) void k_gemm2(const float* __restrict__ X,
                                               const float* __restrict__ Wl,
                                               const float* __restrict__ bl,
                                               const float* __restrict__ Wr,
                                               const float* __restrict__ br,
                                               float* __restrict__ Yl,
                                               float* __restrict__ Yr, int nrows) {
    const int K = 128;
    __shared__ float Xs[64][33];
    __shared__ float Wls[32][NOUT + 1];
    __shared__ float Wrs[32][NOUT + 1];
    const int CN = NOUT / 16;
    int row0 = blockIdx.x * 64;
    int tr = threadIdx.x >> 4;
    int tc = threadIdx.x & 15;
    float accl[4][CN] = {};
    float accr[4][CN] = {};
    for (int k0 = 0; k0 < K; k0 += 32) {
        for (int idx = threadIdx.x; idx < 64 * 32; idx += 256) {
            int r = idx >> 5, k = idx & 31;
            int gr = row0 + r;
            Xs[r][k] = (gr < nrows) ? X[(size_t)gr * K + k0 + k] : 0.f;
        }
        for (int idx = threadIdx.x; idx < NOUT * 32; idx += 256) {
            int o = idx >> 5, k = idx & 31;
            Wls[k][o] = Wl[(size_t)o * K + k0 + k];
            Wrs[k][o] = Wr[(size_t)o * K + k0 + k];
        }
        __syncthreads();
#pragma unroll
        for (int kk = 0; kk < 32; ++kk) {
            float xv[4];
#pragma unroll
            for (int i = 0; i < 4; ++i) xv[i] = Xs[tr * 4 + i][kk];
#pragma unroll
            for (int j = 0; j < CN; ++j) {
                float wl = Wls[kk][j * 16 + tc];
                float wr = Wrs[kk][j * 16 + tc];
#pragma unroll
                for (int i = 0; i < 4; ++i) {
                    accl[i][j] = fmaf(xv[i], wl, accl[i][j]);
                    accr[i][j] = fmaf(xv[i], wr, accr[i][j]);
                }
            }
        }
        __syncthreads();
    }
#pragma unroll
    for (int i = 0; i < 4; ++i) {
        int gr = row0 + tr * 4 + i;
        if (gr >= nrows) continue;
#pragma unroll
        for (int j = 0; j < CN; ++j) {
            int o = j * 16 + tc;
            Yl[(size_t)gr * NOUT + o] = accl[i][j] + bl[o];
            Yr[(size_t)gr * NOUT + o] = accr[i][j] + br[o];
        }
    }
}

// ---------- GATv2 layer 1: H=2, C=64, concat -> out[N][128], fused bias+ELU ----------
__global__ __launch_bounds__(256) void k_gat1(const float* __restrict__ xl,
                                              const float* __restrict__ xr,
                                              const int* __restrict__ rowptr,
                                              const int* __restrict__ csr,
                                              const float* __restrict__ att,
                                              const float* __restrict__ bias,
                                              float* __restrict__ out) {
    int node = blockIdx.x * 4 + (threadIdx.x >> 6);
    if (node >= N_NODES) return;
    int lane = threadIdx.x & 63;
    float a0 = att[lane], a1 = att[64 + lane];
    size_t nb = (size_t)node * 128;
    float xr0 = xr[nb + lane], xr1 = xr[nb + 64 + lane];
    // self loop
    float sl0 = xl[nb + lane], sl1 = xl[nb + 64 + lane];
    float p0 = lrelu(sl0 + xr0) * a0;
    float p1 = lrelu(sl1 + xr1) * a1;
    dred2(p0, p1);
    float w0 = __expf(rl63(p0)), w1 = __expf(rl63(p1));
    float den0 = w0, den1 = w1;
    float acc0 = w0 * sl0, acc1 = w1 * sl1;

    int beg = rowptr[node], end = rowptr[node + 1];
    int cnt = end - beg;
    int npairs = cnt >> 1;
    if (npairs > 0) {
        const int* cp = csr + beg;
        int i0 = cp[0], i1 = cp[1];
        float A0 = xl[(size_t)i0 * 128 + lane], A1 = xl[(size_t)i0 * 128 + 64 + lane];
        float B0 = xl[(size_t)i1 * 128 + lane], B1 = xl[(size_t)i1 * 128 + 64 + lane];
        for (int p = 1; p <= npairs; ++p) {
            float nA0 = 0.f, nA1 = 0.f, nB0 = 0.f, nB1 = 0.f;
            if (p < npairs) {
                int j0 = cp[2 * p], j1 = cp[2 * p + 1];
                nA0 = xl[(size_t)j0 * 128 + lane]; nA1 = xl[(size_t)j0 * 128 + 64 + lane];
                nB0 = xl[(size_t)j1 * 128 + lane]; nB1 = xl[(size_t)j1 * 128 + 64 + lane];
            }
            float pa0 = lrelu(A0 + xr0) * a0;
            float pa1 = lrelu(A1 + xr1) * a1;
            float pb0 = lrelu(B0 + xr0) * a0;
            float pb1 = lrelu(B1 + xr1) * a1;
            dred4(pa0, pa1, pb0, pb1);
            float ea0 = __expf(rl63(pa0)), ea1 = __expf(rl63(pa1));
            float eb0 = __expf(rl63(pb0)), eb1 = __expf(rl63(pb1));
            den0 += ea0 + eb0;
            den1 += ea1 + eb1;
            acc0 = fmaf(ea0, A0, fmaf(eb0, B0, acc0));
            acc1 = fmaf(ea1, A1, fmaf(eb1, B1, acc1));
            A0 = nA0; A1 = nA1; B0 = nB0; B1 = nB1;
        }
    }
    if (cnt & 1) {
        int j = csr[end - 1];
        float C0 = xl[(size_t)j * 128 + lane], C1 = xl[(size_t)j * 128 + 64 + lane];
        float q0 = lrelu(C0 + xr0) * a0;
        float q1 = lrelu(C1 + xr1) * a1;
        dred2(q0, q1);
        float e0 = __expf(rl63(q0)), e1 = __expf(rl63(q1));
        den0 += e0; den1 += e1;
        acc0 = fmaf(e0, C0, acc0);
        acc1 = fmaf(e1, C1, acc1);
    }
    float o0 = acc0 / den0 + bias[lane];
    float o1 = acc1 / den1 + bias[64 + lane];
    out[nb + lane] = o0 > 0.f ? o0 : expm1f(o0);
    out[nb + 64 + lane] = o1 > 0.f ? o1 : expm1f(o1);
}

// ---------- GATv2 layer 2: H=1, C=64 -> out[N][64], fused bias+ELU ----------
__global__ __launch_bounds__(256) void k_gat2(const float* __restrict__ xl,
                                              const float* __restrict__ xr,
                                              const int* __restrict__ rowptr,
                                              const int* __restrict__ csr,
                                              const float* __restrict__ att,
                                              const float* __restrict__ bias,
                                              float* __restrict__ out) {
    int node = blockIdx.x * 4 + (threadIdx.x >> 6);
    if (node >= N_NODES) return;
    int lane = threadIdx.x & 63;
    float a = att[lane];
    size_t nb = (size_t)node * 64;
    float xrv = xr[nb + lane];
    float slv = xl[nb + lane];
    float p = lrelu(slv + xrv) * a;
    dred1(p);
    float w = __expf(rl63(p));
    float den = w;
    float acc = w * slv;

    int beg = rowptr[node], end = rowptr[node + 1];
    int cnt = end - beg;
    int quads = cnt >> 2;
    if (quads > 0) {
        const int* cp = csr + beg;
        int i0 = cp[0], i1 = cp[1], i2 = cp[2], i3 = cp[3];
        float A = xl[(size_t)i0 * 64 + lane];
        float B = xl[(size_t)i1 * 64 + lane];
        float C = xl[(size_t)i2 * 64 + lane];
        float D = xl[(size_t)i3 * 64 + lane];
        for (int q = 1; q <= quads; ++q) {
            float nA = 0.f, nB = 0.f, nC = 0.f, nD = 0.f;
            if (q < quads) {
                int j0 = cp[4 * q], j1 = cp[4 * q + 1], j2 = cp[4 * q + 2], j3 = cp[4 * q + 3];
                nA = xl[(size_t)j0 * 64 + lane];
                nB = xl[(size_t)j1 * 64 + lane];
                nC = xl[(size_t)j2 * 64 + lane];
                nD = xl[(size_t)j3 * 64 + lane];
            }
            float pa = lrelu(A + xrv) * a;
            float pb = lrelu(B + xrv) * a;
            float pc = lrelu(C + xrv) * a;
            float pd = lrelu(D + xrv) * a;
            dred4(pa, pb, pc, pd);
            float ea = __expf(rl63(pa)), eb = __expf(rl63(pb));
            float ec = __expf(rl63(pc)), ed = __expf(rl63(pd));
            den += (ea + eb) + (ec + ed);
            acc = fmaf(ea, A, fmaf(eb, B, fmaf(ec, C, fmaf(ed, D, acc))));
            A = nA; B = nB; C = nC; D = nD;
        }
    }
    int rem = cnt & 3;
    if (rem) {
        int j0 = csr[end - rem];
        int j1 = (rem > 1) ? csr[end - rem + 1] : j0;
        int j2 = (rem > 2) ? csr[end - rem + 2] : j0;
        float A = xl[(size_t)j0 * 64 + lane];
        float B = xl[(size_t)j1 * 64 + lane];
        float C = xl[(size_t)j2 * 64 + lane];
        float pa = lrelu(A + xrv) * a;
        float pb = lrelu(B + xrv) * a;
        float pc = lrelu(C + xrv) * a;
        float pd = 0.f;
        dred4(pa, pb, pc, pd);
        float ea = __expf(rl63(pa));
        float eb = (rem > 1) ? __expf(rl63(pb)) : 0.f;
        float ec = (rem > 2) ? __expf(rl63(pc)) : 0.f;
        den += ea + eb + ec;
        acc = fmaf(ea, A, fmaf(eb, B, fmaf(ec, C, acc)));
    }
    float o = acc / den + bias[lane];
    out[nb + lane] = o > 0.f ? o : expm1f(o);
}

// ---------- classifier head ----------
__global__ __launch_bounds__(256) void k_head(const float* __restrict__ H,
                                              const float* __restrict__ Wc,
                                              const float* __restrict__ bc,
                                              float* __restrict__ out) {
    __shared__ float Ws[NCLS * 64];
    __shared__ float bs[NCLS];
    for (int i = threadIdx.x; i < NCLS * 64; i += 256) Ws[i] = Wc[i];
    if (threadIdx.x < NCLS) bs[threadIdx.x] = bc[threadIdx.x];
    __syncthreads();
    int n = blockIdx.x * 256 + threadIdx.x;
    if (n >= N_NODES) return;
    const float4* hp = (const float4*)(H + (size_t)n * 64);
    float acc[NCLS] = {};
#pragma unroll
    for (int k4 = 0; k4 < 16; ++k4) {
        float4 hv = hp[k4];
#pragma unroll
        for (int c = 0; c < NCLS; ++c) {
            acc[c] = fmaf(hv.x, Ws[c * 64 + k4 * 4 + 0], acc[c]);
            acc[c] = fmaf(hv.y, Ws[c * 64 + k4 * 4 + 1], acc[c]);
            acc[c] = fmaf(hv.z, Ws[c * 64 + k4 * 4 + 2], acc[c]);
            acc[c] = fmaf(hv.w, Ws[c * 64 + k4 * 4 + 3], acc[c]);
        }
    }
#pragma unroll
    for (int c = 0; c < NCLS; ++c) out[(size_t)n * NCLS + c] = acc[c] + bs[c];
}

// ---------- launch ----------
extern "C" void kernel_launch(void* const* d_in, const int* in_sizes, int n_in,
                              void* d_out, int out_size, void* d_ws, size_t ws_size,
                              hipStream_t stream) {
    const float* x     = (const float*)d_in[0];
    const int*   ei    = (const int*)d_in[1];
    const int*   srcp  = ei;
    const int*   dstp  = ei + E_EDGES;
    const float* Wl1   = (const float*)d_in[3];
    const float* bl1   = (const float*)d_in[4];
    const float* Wr1   = (const float*)d_in[5];
    const float* br1   = (const float*)d_in[6];
    const float* att1  = (const float*)d_in[7];
    const float* bias1 = (const float*)d_in[8];
    const float* Wl2   = (const float*)d_in[9];
    const float* bl2   = (const float*)d_in[10];
    const float* Wr2   = (const float*)d_in[11];
    const float* br2   = (const float*)d_in[12];
    const float* att2  = (const float*)d_in[13];
    const float* bias2 = (const float*)d_in[14];
    const float* Wc    = (const float*)d_in[15];
    const float* bc    = (const float*)d_in[16];

    float* fA = (float*)d_ws;                       // xl1 [N,128] -> xl2 [N,64]
    float* fB = fA + (size_t)N_NODES * 128;         // xr1 [N,128] -> xr2 [N,64]
    float* fC = fB + (size_t)N_NODES * 128;         // h1  [N,128] -> h2  [N,64]
    int* rowptr = (int*)(fC + (size_t)N_NODES * 128);
    int* degcur = rowptr + (N_NODES + 1);
    int* csr    = degcur + N_NODES;

    hipMemsetAsync(degcur, 0, N_NODES * sizeof(int), stream);
    k_count<<<(E_EDGES + 255) / 256, 256, 0, stream>>>(dstp, degcur);
    k_scan<<<1, 1024, 0, stream>>>(degcur, rowptr);
    k_scatter<<<(E_EDGES + 255) / 256, 256, 0, stream>>>(srcp, dstp, degcur, csr);

    int gblocks = (N_NODES + 63) / 64;
    k_gemm2<128><<<gblocks, 256, 0, stream>>>(x, Wl1, bl1, Wr1, br1, fA, fB, N_NODES);
    k_gat1<<<(N_NODES + 3) / 4, 256, 0, stream>>>(fA, fB, rowptr, csr, att1, bias1, fC);
    k_gemm2<64><<<gblocks, 256, 0, stream>>>(fC, Wl2, bl2, Wr2, br2, fA, fB, N_NODES);
    k_gat2<<<(N_NODES + 3) / 4, 256, 0, stream>>>(fA, fB, rowptr, csr, att2, bias2, fC);
    k_head<<<(N_NODES + 255) / 256, 256, 0, stream>>>(fC, Wc, bc, (float*)d_out);
}

// Round 5
// 550.681 us; speedup vs baseline: 1.2825x; 1.1296x over previous
//
#include <hip/hip_runtime.h>
#include <hip/hip_bf16.h>

#define N_NODES 50000
#define E_EDGES 800000
#define NCLS 10

typedef short bfrag __attribute__((ext_vector_type(8)));   // 8 bf16 in 4 VGPRs
typedef float f32x4 __attribute__((ext_vector_type(4)));

// ---------- bf16 split helpers ----------
__device__ __forceinline__ unsigned short bf16rne(float x) {
    unsigned u = __float_as_uint(x);
    unsigned r = u + 0x7FFFu + ((u >> 16) & 1u);
    return (unsigned short)(r >> 16);
}

// ---------- DPP wave-64 sum reduction ----------
template <int CTRL, int RM>
__device__ __forceinline__ float dppadd(float x) {
    int s = __builtin_amdgcn_update_dpp(0, __float_as_int(x), CTRL, RM, 0xf, true);
    return x + __int_as_float(s);
}
__device__ __forceinline__ float rl63(float x) {
    return __int_as_float(__builtin_amdgcn_readlane(__float_as_int(x), 63));
}
__device__ __forceinline__ void dred1(float& x0) {
    x0 = dppadd<0x111, 0xf>(x0);
    x0 = dppadd<0x112, 0xf>(x0);
    x0 = dppadd<0x114, 0xf>(x0);
    x0 = dppadd<0x118, 0xf>(x0);
    x0 = dppadd<0x142, 0xa>(x0);
    x0 = dppadd<0x143, 0xc>(x0);
}
__device__ __forceinline__ void dred2(float& x0, float& x1) {
    x0 = dppadd<0x111, 0xf>(x0); x1 = dppadd<0x111, 0xf>(x1);
    x0 = dppadd<0x112, 0xf>(x0); x1 = dppadd<0x112, 0xf>(x1);
    x0 = dppadd<0x114, 0xf>(x0); x1 = dppadd<0x114, 0xf>(x1);
    x0 = dppadd<0x118, 0xf>(x0); x1 = dppadd<0x118, 0xf>(x1);
    x0 = dppadd<0x142, 0xa>(x0); x1 = dppadd<0x142, 0xa>(x1);
    x0 = dppadd<0x143, 0xc>(x0); x1 = dppadd<0x143, 0xc>(x1);
}
__device__ __forceinline__ void dred4(float& x0, float& x1, float& x2, float& x3) {
    x0 = dppadd<0x111, 0xf>(x0); x1 = dppadd<0x111, 0xf>(x1);
    x2 = dppadd<0x111, 0xf>(x2); x3 = dppadd<0x111, 0xf>(x3);
    x0 = dppadd<0x112, 0xf>(x0); x1 = dppadd<0x112, 0xf>(x1);
    x2 = dppadd<0x112, 0xf>(x2); x3 = dppadd<0x112, 0xf>(x3);
    x0 = dppadd<0x114, 0xf>(x0); x1 = dppadd<0x114, 0xf>(x1);
    x2 = dppadd<0x114, 0xf>(x2); x3 = dppadd<0x114, 0xf>(x3);
    x0 = dppadd<0x118, 0xf>(x0); x1 = dppadd<0x118, 0xf>(x1);
    x2 = dppadd<0x118, 0xf>(x2); x3 = dppadd<0x118, 0xf>(x3);
    x0 = dppadd<0x142, 0xa>(x0); x1 = dppadd<0x142, 0xa>(x1);
    x2 = dppadd<0x142, 0xa>(x2); x3 = dppadd<0x142, 0xa>(x3);
    x0 = dppadd<0x143, 0xc>(x0); x1 = dppadd<0x143, 0xc>(x1);
    x2 = dppadd<0x143, 0xc>(x2); x3 = dppadd<0x143, 0xc>(x3);
}
__device__ __forceinline__ float lrelu(float u) { return u > 0.f ? u : 0.2f * u; }

// ---------- CSR build ----------
__global__ void k_count(const int* __restrict__ dst, int* __restrict__ deg) {
    int i = blockIdx.x * blockDim.x + threadIdx.x;
    if (i < E_EDGES) {
        unsigned d = (unsigned)dst[i];
        if (d < N_NODES) atomicAdd(&deg[d], 1);
    }
}

__global__ void k_scan(int* __restrict__ degcur, int* __restrict__ rowptr) {
    __shared__ int sums[1024];
    const int CH = 49;
    int t = threadIdx.x;
    int beg = t * CH;
    int end = min(beg + CH, N_NODES);
    int s = 0;
    for (int i = beg; i < end; ++i) s += degcur[i];
    sums[t] = s;
    __syncthreads();
    for (int off = 1; off < 1024; off <<= 1) {
        int v = (t >= off) ? sums[t - off] : 0;
        __syncthreads();
        sums[t] += v;
        __syncthreads();
    }
    int run = (t == 0) ? 0 : sums[t - 1];
    for (int i = beg; i < end; ++i) {
        int d = degcur[i];
        rowptr[i] = run;
        degcur[i] = run;
        run += d;
    }
    if (t == 1023) rowptr[N_NODES] = sums[1023];
}

__global__ void k_scatter(const int* __restrict__ src, const int* __restrict__ dst,
                          int* __restrict__ cursor, int* __restrict__ csr_src) {
    int i = blockIdx.x * blockDim.x + threadIdx.x;
    if (i < E_EDGES) {
        unsigned d = (unsigned)dst[i];
        if (d < N_NODES) {
            int p = atomicAdd(&cursor[d], 1);
            unsigned s = (unsigned)src[i];
            csr_src[p] = (s < N_NODES) ? (int)s : 0;
        }
    }
}

// ---------- split fp32 weight -> hi/lo bf16 ----------
__global__ void k_splitW(const float* __restrict__ W, int n,
                         short* __restrict__ hi, short* __restrict__ lo) {
    int i = blockIdx.x * 256 + threadIdx.x;
    if (i < n) {
        float x = W[i];
        unsigned short h = bf16rne(x);
        float hf = __uint_as_float((unsigned)h << 16);
        unsigned short l = bf16rne(x - hf);
        hi[i] = (short)h;
        lo[i] = (short)l;
    }
}

// ---------- MFMA dual GEMM (split-bf16 fp32 emulation) ----------
// Yl[n][NCT*16] = X[n][128] @ Wl^T + bl ; same for r. W pre-split hi/lo bf16,
// X split on the fly. A/B frags: 8 contiguous-K bf16 per lane (row/col=lane&15,
// k-chunk=lane>>4). C/D: col=lane&15, row=(lane>>4)*4+reg (m89-verified).
template <int NCT>
__global__ __launch_bounds__(256) void k_mgemm(const float* __restrict__ X,
                                               const short* __restrict__ whl,
                                               const short* __restrict__ wll,
                                               const short* __restrict__ whr,
                                               const short* __restrict__ wlr,
                                               const float* __restrict__ bl,
                                               const float* __restrict__ br,
                                               float* __restrict__ Yl,
                                               float* __restrict__ Yr, int nrows) {
    const int NOUT = NCT * 16;
    int tid = threadIdx.x;
    int wv = tid >> 6, lane = tid & 63;
    int m = lane & 15, g = lane >> 4;
    int row = blockIdx.x * 64 + wv * 16 + m;
    int rowc = min(row, nrows - 1);

    // load + split A: 4 k-steps x 8 contiguous floats per lane
    bfrag ahi[4], alo[4];
    const float* xp = X + (size_t)rowc * 128 + g * 8;
#pragma unroll
    for (int kb = 0; kb < 4; ++kb) {
        float4 u0 = *(const float4*)(xp + kb * 32);
        float4 u1 = *(const float4*)(xp + kb * 32 + 4);
        float xs[8] = {u0.x, u0.y, u0.z, u0.w, u1.x, u1.y, u1.z, u1.w};
#pragma unroll
        for (int j = 0; j < 8; ++j) {
            unsigned short h = bf16rne(xs[j]);
            float hf = __uint_as_float((unsigned)h << 16);
            unsigned short l = bf16rne(xs[j] - hf);
            ahi[kb][j] = (short)h;
            alo[kb][j] = (short)l;
        }
    }

    f32x4 accl[NCT], accr[NCT];
#pragma unroll
    for (int ct = 0; ct < NCT; ++ct) {
        accl[ct] = (f32x4){0.f, 0.f, 0.f, 0.f};
        accr[ct] = (f32x4){0.f, 0.f, 0.f, 0.f};
    }

#pragma unroll
    for (int kb = 0; kb < 4; ++kb) {
#pragma unroll
        for (int ct = 0; ct < NCT; ++ct) {
            size_t wo = (size_t)(ct * 16 + m) * 128 + kb * 32 + g * 8;
            bfrag bhl = *(const bfrag*)(whl + wo);
            bfrag bll = *(const bfrag*)(wll + wo);
            bfrag bhr = *(const bfrag*)(whr + wo);
            bfrag blr = *(const bfrag*)(wlr + wo);
            accl[ct] = __builtin_amdgcn_mfma_f32_16x16x32_bf16(ahi[kb], bhl, accl[ct], 0, 0, 0);
            accl[ct] = __builtin_amdgcn_mfma_f32_16x16x32_bf16(alo[kb], bhl, accl[ct], 0, 0, 0);
            accl[ct] = __builtin_amdgcn_mfma_f32_16x16x32_bf16(ahi[kb], bll, accl[ct], 0, 0, 0);
            accr[ct] = __builtin_amdgcn_mfma_f32_16x16x32_bf16(ahi[kb], bhr, accr[ct], 0, 0, 0);
            accr[ct] = __builtin_amdgcn_mfma_f32_16x16x32_bf16(alo[kb], bhr, accr[ct], 0, 0, 0);
            accr[ct] = __builtin_amdgcn_mfma_f32_16x16x32_bf16(ahi[kb], blr, accr[ct], 0, 0, 0);
        }
    }

    int orow0 = blockIdx.x * 64 + wv * 16 + g * 4;
#pragma unroll
    for (int ct = 0; ct < NCT; ++ct) {
        int col = ct * 16 + m;
        float blv = bl[col], brv = br[col];
#pragma unroll
        for (int i = 0; i < 4; ++i) {
            int orow = orow0 + i;
            if (orow < nrows) {
                Yl[(size_t)orow * NOUT + col] = accl[ct][i] + blv;
                Yr[(size_t)orow * NOUT + col] = accr[ct][i] + brv;
            }
        }
    }
}

// ---------- GATv2 layer 1: H=2, C=64, concat -> out[N][128], fused bias+ELU ----------
__global__ __launch_bounds__(256) void k_gat1(const float* __restrict__ xl,
                                              const float* __restrict__ xr,
                                              const int* __restrict__ rowptr,
                                              const int* __restrict__ csr,
                                              const float* __restrict__ att,
                                              const float* __restrict__ bias,
                                              float* __restrict__ out) {
    int node = blockIdx.x * 4 + (threadIdx.x >> 6);
    if (node >= N_NODES) return;
    int lane = threadIdx.x & 63;
    float a0 = att[lane], a1 = att[64 + lane];
    size_t nb = (size_t)node * 128;
    float xr0 = xr[nb + lane], xr1 = xr[nb + 64 + lane];
    float sl0 = xl[nb + lane], sl1 = xl[nb + 64 + lane];
    float p0 = lrelu(sl0 + xr0) * a0;
    float p1 = lrelu(sl1 + xr1) * a1;
    dred2(p0, p1);
    float w0 = __expf(rl63(p0)), w1 = __expf(rl63(p1));
    float den0 = w0, den1 = w1;
    float acc0 = w0 * sl0, acc1 = w1 * sl1;

    int beg = rowptr[node], end = rowptr[node + 1];
    int cnt = end - beg;
    int npairs = cnt >> 1;
    if (npairs > 0) {
        const int* cp = csr + beg;
        int i0 = cp[0], i1 = cp[1];
        float A0 = xl[(size_t)i0 * 128 + lane], A1 = xl[(size_t)i0 * 128 + 64 + lane];
        float B0 = xl[(size_t)i1 * 128 + lane], B1 = xl[(size_t)i1 * 128 + 64 + lane];
        for (int p = 1; p <= npairs; ++p) {
            float nA0 = 0.f, nA1 = 0.f, nB0 = 0.f, nB1 = 0.f;
            if (p < npairs) {
                int j0 = cp[2 * p], j1 = cp[2 * p + 1];
                nA0 = xl[(size_t)j0 * 128 + lane]; nA1 = xl[(size_t)j0 * 128 + 64 + lane];
                nB0 = xl[(size_t)j1 * 128 + lane]; nB1 = xl[(size_t)j1 * 128 + 64 + lane];
            }
            float pa0 = lrelu(A0 + xr0) * a0;
            float pa1 = lrelu(A1 + xr1) * a1;
            float pb0 = lrelu(B0 + xr0) * a0;
            float pb1 = lrelu(B1 + xr1) * a1;
            dred4(pa0, pa1, pb0, pb1);
            float ea0 = __expf(rl63(pa0)), ea1 = __expf(rl63(pa1));
            float eb0 = __expf(rl63(pb0)), eb1 = __expf(rl63(pb1));
            den0 += ea0 + eb0;
            den1 += ea1 + eb1;
            acc0 = fmaf(ea0, A0, fmaf(eb0, B0, acc0));
            acc1 = fmaf(ea1, A1, fmaf(eb1, B1, acc1));
            A0 = nA0; A1 = nA1; B0 = nB0; B1 = nB1;
        }
    }
    if (cnt & 1) {
        int j = csr[end - 1];
        float C0 = xl[(size_t)j * 128 + lane], C1 = xl[(size_t)j * 128 + 64 + lane];
        float q0 = lrelu(C0 + xr0) * a0;
        float q1 = lrelu(C1 + xr1) * a1;
        dred2(q0, q1);
        float e0 = __expf(rl63(q0)), e1 = __expf(rl63(q1));
        den0 += e0; den1 += e1;
        acc0 = fmaf(e0, C0, acc0);
        acc1 = fmaf(e1, C1, acc1);
    }
    float o0 = acc0 / den0 + bias[lane];
    float o1 = acc1 / den1 + bias[64 + lane];
    out[nb + lane] = o0 > 0.f ? o0 : expm1f(o0);
    out[nb + 64 + lane] = o1 > 0.f ? o1 : expm1f(o1);
}

// ---------- GATv2 layer 2: H=1, C=64 -> out[N][64], fused bias+ELU ----------
__global__ __launch_bounds__(256) void k_gat2(const float* __restrict__ xl,
                                              const float* __restrict__ xr,
                                              const int* __restrict__ rowptr,
                                              const int* __restrict__ csr,
                                              const float* __restrict__ att,
                                              const float* __restrict__ bias,
                                              float* __restrict__ out) {
    int node = blockIdx.x * 4 + (threadIdx.x >> 6);
    if (node >= N_NODES) return;
    int lane = threadIdx.x & 63;
    float a = att[lane];
    size_t nb = (size_t)node * 64;
    float xrv = xr[nb + lane];
    float slv = xl[nb + lane];
    float p = lrelu(slv + xrv) * a;
    dred1(p);
    float w = __expf(rl63(p));
    float den = w;
    float acc = w * slv;

    int beg = rowptr[node], end = rowptr[node + 1];
    int cnt = end - beg;
    int quads = cnt >> 2;
    if (quads > 0) {
        const int* cp = csr + beg;
        int i0 = cp[0], i1 = cp[1], i2 = cp[2], i3 = cp[3];
        float A = xl[(size_t)i0 * 64 + lane];
        float B = xl[(size_t)i1 * 64 + lane];
        float C = xl[(size_t)i2 * 64 + lane];
        float D = xl[(size_t)i3 * 64 + lane];
        for (int q = 1; q <= quads; ++q) {
            float nA = 0.f, nB = 0.f, nC = 0.f, nD = 0.f;
            if (q < quads) {
                int j0 = cp[4 * q], j1 = cp[4 * q + 1], j2 = cp[4 * q + 2], j3 = cp[4 * q + 3];
                nA = xl[(size_t)j0 * 64 + lane];
                nB = xl[(size_t)j1 * 64 + lane];
                nC = xl[(size_t)j2 * 64 + lane];
                nD = xl[(size_t)j3 * 64 + lane];
            }
            float pa = lrelu(A + xrv) * a;
            float pb = lrelu(B + xrv) * a;
            float pc = lrelu(C + xrv) * a;
            float pd = lrelu(D + xrv) * a;
            dred4(pa, pb, pc, pd);
            float ea = __expf(rl63(pa)), eb = __expf(rl63(pb));
            float ec = __expf(rl63(pc)), ed = __expf(rl63(pd));
            den += (ea + eb) + (ec + ed);
            acc = fmaf(ea, A, fmaf(eb, B, fmaf(ec, C, fmaf(ed, D, acc))));
            A = nA; B = nB; C = nC; D = nD;
        }
    }
    int rem = cnt & 3;
    if (rem) {
        int j0 = csr[end - rem];
        int j1 = (rem > 1) ? csr[end - rem + 1] : j0;
        int j2 = (rem > 2) ? csr[end - rem + 2] : j0;
        float A = xl[(size_t)j0 * 64 + lane];
        float B = xl[(size_t)j1 * 64 + lane];
        float C = xl[(size_t)j2 * 64 + lane];
        float pa = lrelu(A + xrv) * a;
        float pb = lrelu(B + xrv) * a;
        float pc = lrelu(C + xrv) * a;
        float pd = 0.f;
        dred4(pa, pb, pc, pd);
        float ea = __expf(rl63(pa));
        float eb = (rem > 1) ? __expf(rl63(pb)) : 0.f;
        float ec = (rem > 2) ? __expf(rl63(pc)) : 0.f;
        den += ea + eb + ec;
        acc = fmaf(ea, A, fmaf(eb, B, fmaf(ec, C, acc)));
    }
    float o = acc / den + bias[lane];
    out[nb + lane] = o > 0.f ? o : expm1f(o);
}

// ---------- classifier head ----------
__global__ __launch_bounds__(256) void k_head(const float* __restrict__ H,
                                              const float* __restrict__ Wc,
                                              const float* __restrict__ bc,
                                              float* __restrict__ out) {
    __shared__ float Ws[NCLS * 64];
    __shared__ float bs[NCLS];
    for (int i = threadIdx.x; i < NCLS * 64; i += 256) Ws[i] = Wc[i];
    if (threadIdx.x < NCLS) bs[threadIdx.x] = bc[threadIdx.x];
    __syncthreads();
    int n = blockIdx.x * 256 + threadIdx.x;
    if (n >= N_NODES) return;
    const float4* hp = (const float4*)(H + (size_t)n * 64);
    float acc[NCLS] = {};
#pragma unroll
    for (int k4 = 0; k4 < 16; ++k4) {
        float4 hv = hp[k4];
#pragma unroll
        for (int c = 0; c < NCLS; ++c) {
            acc[c] = fmaf(hv.x, Ws[c * 64 + k4 * 4 + 0], acc[c]);
            acc[c] = fmaf(hv.y, Ws[c * 64 + k4 * 4 + 1], acc[c]);
            acc[c] = fmaf(hv.z, Ws[c * 64 + k4 * 4 + 2], acc[c]);
            acc[c] = fmaf(hv.w, Ws[c * 64 + k4 * 4 + 3], acc[c]);
        }
    }
#pragma unroll
    for (int c = 0; c < NCLS; ++c) out[(size_t)n * NCLS + c] = acc[c] + bs[c];
}

// ---------- launch ----------
extern "C" void kernel_launch(void* const* d_in, const int* in_sizes, int n_in,
                              void* d_out, int out_size, void* d_ws, size_t ws_size,
                              hipStream_t stream) {
    const float* x     = (const float*)d_in[0];
    const int*   ei    = (const int*)d_in[1];
    const int*   srcp  = ei;
    const int*   dstp  = ei + E_EDGES;
    const float* Wl1   = (const float*)d_in[3];
    const float* bl1   = (const float*)d_in[4];
    const float* Wr1   = (const float*)d_in[5];
    const float* br1   = (const float*)d_in[6];
    const float* att1  = (const float*)d_in[7];
    const float* bias1 = (const float*)d_in[8];
    const float* Wl2   = (const float*)d_in[9];
    const float* bl2   = (const float*)d_in[10];
    const float* Wr2   = (const float*)d_in[11];
    const float* br2   = (const float*)d_in[12];
    const float* att2  = (const float*)d_in[13];
    const float* bias2 = (const float*)d_in[14];
    const float* Wc    = (const float*)d_in[15];
    const float* bc    = (const float*)d_in[16];

    float* fA = (float*)d_ws;                       // xl1 [N,128] -> xl2 [N,64]
    float* fB = fA + (size_t)N_NODES * 128;         // xr1 [N,128] -> xr2 [N,64]
    float* fC = fB + (size_t)N_NODES * 128;         // h1  [N,128] -> h2  [N,64]
    int* rowptr = (int*)(fC + (size_t)N_NODES * 128);
    int* degcur = rowptr + (N_NODES + 1);
    int* csr    = degcur + N_NODES;
    // 16B-aligned bf16 weight splits after csr
    size_t woff = ((size_t)(csr + E_EDGES) - (size_t)d_ws + 15) & ~(size_t)15;
    short* whiL = (short*)((char*)d_ws + woff);     // 16384 each
    short* wloL = whiL + 16384;
    short* whiR = wloL + 16384;
    short* wloR = whiR + 16384;

    hipMemsetAsync(degcur, 0, N_NODES * sizeof(int), stream);
    k_count<<<(E_EDGES + 255) / 256, 256, 0, stream>>>(dstp, degcur);
    k_scan<<<1, 1024, 0, stream>>>(degcur, rowptr);
    k_scatter<<<(E_EDGES + 255) / 256, 256, 0, stream>>>(srcp, dstp, degcur, csr);

    int gblocks = (N_NODES + 63) / 64;

    // conv1: split weights, MFMA dual GEMM, gat
    k_splitW<<<64, 256, 0, stream>>>(Wl1, 16384, whiL, wloL);
    k_splitW<<<64, 256, 0, stream>>>(Wr1, 16384, whiR, wloR);
    k_mgemm<8><<<gblocks, 256, 0, stream>>>(x, whiL, wloL, whiR, wloR, bl1, br1, fA, fB, N_NODES);
    k_gat1<<<(N_NODES + 3) / 4, 256, 0, stream>>>(fA, fB, rowptr, csr, att1, bias1, fC);

    // conv2
    k_splitW<<<32, 256, 0, stream>>>(Wl2, 8192, whiL, wloL);
    k_splitW<<<32, 256, 0, stream>>>(Wr2, 8192, whiR, wloR);
    k_mgemm<4><<<gblocks, 256, 0, stream>>>(fC, whiL, wloL, whiR, wloR, bl2, br2, fA, fB, N_NODES);
    k_gat2<<<(N_NODES + 3) / 4, 256, 0, stream>>>(fA, fB, rowptr, csr, att2, bias2, fC);

    k_head<<<(N_NODES + 255) / 256, 256, 0, stream>>>(fC, Wc, bc, (float*)d_out);
}

// Round 7
// 442.675 us; speedup vs baseline: 1.5954x; 1.2440x over previous
//
#include <hip/hip_runtime.h>
#include <hip/hip_bf16.h>

#define N_NODES 50000
#define E_EDGES 800000
#define NCLS 10
#define SCAN_BLOCKS 196   // 196*256 = 50176 >= N_NODES

typedef short bfrag __attribute__((ext_vector_type(8)));   // 8 bf16 in 4 VGPRs
typedef float f32x4 __attribute__((ext_vector_type(4)));

// ---------- bf16 split helpers ----------
__device__ __forceinline__ unsigned short bf16rne(float x) {
    unsigned u = __float_as_uint(x);
    unsigned r = u + 0x7FFFu + ((u >> 16) & 1u);
    return (unsigned short)(r >> 16);
}

// ---------- DPP wave-64 sum reduction ----------
template <int CTRL, int RM>
__device__ __forceinline__ float dppadd(float x) {
    int s = __builtin_amdgcn_update_dpp(0, __float_as_int(x), CTRL, RM, 0xf, true);
    return x + __int_as_float(s);
}
__device__ __forceinline__ float rl63(float x) {
    return __int_as_float(__builtin_amdgcn_readlane(__float_as_int(x), 63));
}
__device__ __forceinline__ void dred1(float& x0) {
    x0 = dppadd<0x111, 0xf>(x0);
    x0 = dppadd<0x112, 0xf>(x0);
    x0 = dppadd<0x114, 0xf>(x0);
    x0 = dppadd<0x118, 0xf>(x0);
    x0 = dppadd<0x142, 0xa>(x0);
    x0 = dppadd<0x143, 0xc>(x0);
}
__device__ __forceinline__ void dred2(float& x0, float& x1) {
    x0 = dppadd<0x111, 0xf>(x0); x1 = dppadd<0x111, 0xf>(x1);
    x0 = dppadd<0x112, 0xf>(x0); x1 = dppadd<0x112, 0xf>(x1);
    x0 = dppadd<0x114, 0xf>(x0); x1 = dppadd<0x114, 0xf>(x1);
    x0 = dppadd<0x118, 0xf>(x0); x1 = dppadd<0x118, 0xf>(x1);
    x0 = dppadd<0x142, 0xa>(x0); x1 = dppadd<0x142, 0xa>(x1);
    x0 = dppadd<0x143, 0xc>(x0); x1 = dppadd<0x143, 0xc>(x1);
}
__device__ __forceinline__ void dred4(float& x0, float& x1, float& x2, float& x3) {
    x0 = dppadd<0x111, 0xf>(x0); x1 = dppadd<0x111, 0xf>(x1);
    x2 = dppadd<0x111, 0xf>(x2); x3 = dppadd<0x111, 0xf>(x3);
    x0 = dppadd<0x112, 0xf>(x0); x1 = dppadd<0x112, 0xf>(x1);
    x2 = dppadd<0x112, 0xf>(x2); x3 = dppadd<0x112, 0xf>(x3);
    x0 = dppadd<0x114, 0xf>(x0); x1 = dppadd<0x114, 0xf>(x1);
    x2 = dppadd<0x114, 0xf>(x2); x3 = dppadd<0x114, 0xf>(x3);
    x0 = dppadd<0x118, 0xf>(x0); x1 = dppadd<0x118, 0xf>(x1);
    x2 = dppadd<0x118, 0xf>(x2); x3 = dppadd<0x118, 0xf>(x3);
    x0 = dppadd<0x142, 0xa>(x0); x1 = dppadd<0x142, 0xa>(x1);
    x2 = dppadd<0x142, 0xa>(x2); x3 = dppadd<0x142, 0xa>(x3);
    x0 = dppadd<0x143, 0xc>(x0); x1 = dppadd<0x143, 0xc>(x1);
    x2 = dppadd<0x143, 0xc>(x2); x3 = dppadd<0x143, 0xc>(x3);
}
__device__ __forceinline__ float lrelu(float u) { return u > 0.f ? u : 0.2f * u; }

// ---------- CSR build ----------
__global__ void k_count(const int* __restrict__ dst, int* __restrict__ deg) {
    int i = blockIdx.x * blockDim.x + threadIdx.x;
    if (i < E_EDGES) {
        unsigned d = (unsigned)dst[i];
        if (d < N_NODES) atomicAdd(&deg[d], 1);
    }
}

// hierarchical exclusive scan, 3 passes, all parallel
__global__ void k_scanA(const int* __restrict__ deg, int* __restrict__ incl,
                        int* __restrict__ bsum) {
    __shared__ int s[256];
    int i = blockIdx.x * 256 + threadIdx.x;
    int v = (i < N_NODES) ? deg[i] : 0;
    s[threadIdx.x] = v;
    __syncthreads();
    for (int off = 1; off < 256; off <<= 1) {
        int t = (threadIdx.x >= off) ? s[threadIdx.x - off] : 0;
        __syncthreads();
        s[threadIdx.x] += t;
        __syncthreads();
    }
    if (i < N_NODES) incl[i] = s[threadIdx.x];
    if (threadIdx.x == 255) bsum[blockIdx.x] = s[255];
}

__global__ void k_scanB(int* __restrict__ bsum) {
    __shared__ int s[256];
    int t = threadIdx.x;
    s[t] = (t < SCAN_BLOCKS) ? bsum[t] : 0;
    __syncthreads();
    for (int off = 1; off < 256; off <<= 1) {
        int v = (t >= off) ? s[t - off] : 0;
        __syncthreads();
        s[t] += v;
        __syncthreads();
    }
    if (t < SCAN_BLOCKS) bsum[t] = s[t];  // inclusive block sums
}

__global__ void k_scanC(int* __restrict__ degcur, const int* __restrict__ incl,
                        const int* __restrict__ bsum, int* __restrict__ rowptr) {
    int i = blockIdx.x * 256 + threadIdx.x;
    if (i >= N_NODES) return;
    int base = (blockIdx.x == 0) ? 0 : bsum[blockIdx.x - 1];
    int d = degcur[i];
    int excl = base + incl[i] - d;
    rowptr[i] = excl;
    degcur[i] = excl;  // cursor init
    if (i == N_NODES - 1) rowptr[N_NODES] = base + incl[i];
}

__global__ void k_scatter(const int* __restrict__ src, const int* __restrict__ dst,
                          int* __restrict__ cursor, int* __restrict__ csr_src) {
    int i = blockIdx.x * blockDim.x + threadIdx.x;
    if (i < E_EDGES) {
        unsigned d = (unsigned)dst[i];
        if (d < N_NODES) {
            int p = atomicAdd(&cursor[d], 1);
            unsigned s = (unsigned)src[i];
            csr_src[p] = (s < N_NODES) ? (int)s : 0;
        }
    }
}

// ---------- split fp32 weight -> hi/lo bf16 ----------
__global__ void k_splitW(const float* __restrict__ W, int n,
                         short* __restrict__ hi, short* __restrict__ lo) {
    int i = blockIdx.x * 256 + threadIdx.x;
    if (i < n) {
        float x = W[i];
        unsigned short h = bf16rne(x);
        float hf = __uint_as_float((unsigned)h << 16);
        unsigned short l = bf16rne(x - hf);
        hi[i] = (short)h;
        lo[i] = (short)l;
    }
}

// ---------- MFMA dual GEMM (split-bf16 fp32 emulation) ----------
template <int NCT>
__global__ __launch_bounds__(256) void k_mgemm(const float* __restrict__ X,
                                               const short* __restrict__ whl,
                                               const short* __restrict__ wll,
                                               const short* __restrict__ whr,
                                               const short* __restrict__ wlr,
                                               const float* __restrict__ bl,
                                               const float* __restrict__ br,
                                               float* __restrict__ Yl,
                                               float* __restrict__ Yr, int nrows) {
    const int NOUT = NCT * 16;
    int tid = threadIdx.x;
    int wv = tid >> 6, lane = tid & 63;
    int m = lane & 15, g = lane >> 4;
    int row = blockIdx.x * 64 + wv * 16 + m;
    int rowc = min(row, nrows - 1);

    bfrag ahi[4], alo[4];
    const float* xp = X + (size_t)rowc * 128 + g * 8;
#pragma unroll
    for (int kb = 0; kb < 4; ++kb) {
        float4 u0 = *(const float4*)(xp + kb * 32);
        float4 u1 = *(const float4*)(xp + kb * 32 + 4);
        float xs[8] = {u0.x, u0.y, u0.z, u0.w, u1.x, u1.y, u1.z, u1.w};
#pragma unroll
        for (int j = 0; j < 8; ++j) {
            unsigned short h = bf16rne(xs[j]);
            float hf = __uint_as_float((unsigned)h << 16);
            unsigned short l = bf16rne(xs[j] - hf);
            ahi[kb][j] = (short)h;
            alo[kb][j] = (short)l;
        }
    }

    f32x4 accl[NCT], accr[NCT];
#pragma unroll
    for (int ct = 0; ct < NCT; ++ct) {
        accl[ct] = (f32x4){0.f, 0.f, 0.f, 0.f};
        accr[ct] = (f32x4){0.f, 0.f, 0.f, 0.f};
    }

#pragma unroll
    for (int kb = 0; kb < 4; ++kb) {
#pragma unroll
        for (int ct = 0; ct < NCT; ++ct) {
            size_t wo = (size_t)(ct * 16 + m) * 128 + kb * 32 + g * 8;
            bfrag bhl = *(const bfrag*)(whl + wo);
            bfrag bll = *(const bfrag*)(wll + wo);
            bfrag bhr = *(const bfrag*)(whr + wo);
            bfrag blr = *(const bfrag*)(wlr + wo);
            accl[ct] = __builtin_amdgcn_mfma_f32_16x16x32_bf16(ahi[kb], bhl, accl[ct], 0, 0, 0);
            accl[ct] = __builtin_amdgcn_mfma_f32_16x16x32_bf16(alo[kb], bhl, accl[ct], 0, 0, 0);
            accl[ct] = __builtin_amdgcn_mfma_f32_16x16x32_bf16(ahi[kb], bll, accl[ct], 0, 0, 0);
            accr[ct] = __builtin_amdgcn_mfma_f32_16x16x32_bf16(ahi[kb], bhr, accr[ct], 0, 0, 0);
            accr[ct] = __builtin_amdgcn_mfma_f32_16x16x32_bf16(alo[kb], bhr, accr[ct], 0, 0, 0);
            accr[ct] = __builtin_amdgcn_mfma_f32_16x16x32_bf16(ahi[kb], blr, accr[ct], 0, 0, 0);
        }
    }

    int orow0 = blockIdx.x * 64 + wv * 16 + g * 4;
#pragma unroll
    for (int ct = 0; ct < NCT; ++ct) {
        int col = ct * 16 + m;
        float blv = bl[col], brv = br[col];
#pragma unroll
        for (int i = 0; i < 4; ++i) {
            int orow = orow0 + i;
            if (orow < nrows) {
                Yl[(size_t)orow * NOUT + col] = accl[ct][i] + blv;
                Yr[(size_t)orow * NOUT + col] = accr[ct][i] + brv;
            }
        }
    }
}

// ---------- GATv2 layer 1: H=2, C=64, concat -> out[N][128], fused bias+ELU ----------
__global__ __launch_bounds__(256) void k_gat1(const float* __restrict__ xl,
                                              const float* __restrict__ xr,
                                              const int* __restrict__ rowptr,
                                              const int* __restrict__ csr,
                                              const float* __restrict__ att,
                                              const float* __restrict__ bias,
                                              float* __restrict__ out) {
    int node = blockIdx.x * 4 + (threadIdx.x >> 6);
    if (node >= N_NODES) return;
    int lane = threadIdx.x & 63;
    float a0 = att[lane], a1 = att[64 + lane];
    size_t nb = (size_t)node * 128;
    float xr0 = xr[nb + lane], xr1 = xr[nb + 64 + lane];
    float sl0 = xl[nb + lane], sl1 = xl[nb + 64 + lane];
    float p0 = lrelu(sl0 + xr0) * a0;
    float p1 = lrelu(sl1 + xr1) * a1;
    dred2(p0, p1);
    float w0 = __expf(rl63(p0)), w1 = __expf(rl63(p1));
    float den0 = w0, den1 = w1;
    float acc0 = w0 * sl0, acc1 = w1 * sl1;

    int beg = rowptr[node], end = rowptr[node + 1];
    int cnt = end - beg;
    int npairs = cnt >> 1;
    if (npairs > 0) {
        const int* cp = csr + beg;
        int i0 = cp[0], i1 = cp[1];
        float A0 = xl[(size_t)i0 * 128 + lane], A1 = xl[(size_t)i0 * 128 + 64 + lane];
        float B0 = xl[(size_t)i1 * 128 + lane], B1 = xl[(size_t)i1 * 128 + 64 + lane];
        for (int p = 1; p <= npairs; ++p) {
            float nA0 = 0.f, nA1 = 0.f, nB0 = 0.f, nB1 = 0.f;
            if (p < npairs) {
                int j0 = cp[2 * p], j1 = cp[2 * p + 1];
                nA0 = xl[(size_t)j0 * 128 + lane]; nA1 = xl[(size_t)j0 * 128 + 64 + lane];
                nB0 = xl[(size_t)j1 * 128 + lane]; nB1 = xl[(size_t)j1 * 128 + 64 + lane];
            }
            float pa0 = lrelu(A0 + xr0) * a0;
            float pa1 = lrelu(A1 + xr1) * a1;
            float pb0 = lrelu(B0 + xr0) * a0;
            float pb1 = lrelu(B1 + xr1) * a1;
            dred4(pa0, pa1, pb0, pb1);
            float ea0 = __expf(rl63(pa0)), ea1 = __expf(rl63(pa1));
            float eb0 = __expf(rl63(pb0)), eb1 = __expf(rl63(pb1));
            den0 += ea0 + eb0;
            den1 += ea1 + eb1;
            acc0 = fmaf(ea0, A0, fmaf(eb0, B0, acc0));
            acc1 = fmaf(ea1, A1, fmaf(eb1, B1, acc1));
            A0 = nA0; A1 = nA1; B0 = nB0; B1 = nB1;
        }
    }
    if (cnt & 1) {
        int j = csr[end - 1];
        float C0 = xl[(size_t)j * 128 + lane], C1 = xl[(size_t)j * 128 + 64 + lane];
        float q0 = lrelu(C0 + xr0) * a0;
        float q1 = lrelu(C1 + xr1) * a1;
        dred2(q0, q1);
        float e0 = __expf(rl63(q0)), e1 = __expf(rl63(q1));
        den0 += e0; den1 += e1;
        acc0 = fmaf(e0, C0, acc0);
        acc1 = fmaf(e1, C1, acc1);
    }
    float o0 = acc0 / den0 + bias[lane];
    float o1 = acc1 / den1 + bias[64 + lane];
    out[nb + lane] = o0 > 0.f ? o0 : expm1f(o0);
    out[nb + 64 + lane] = o1 > 0.f ? o1 : expm1f(o1);
}

// ---------- GATv2 layer 2: H=1, C=64 -> out[N][64], fused bias+ELU ----------
__global__ __launch_bounds__(256) void k_gat2(const float* __restrict__ xl,
                                              const float* __restrict__ xr,
                                              const int* __restrict__ rowptr,
                                              const int* __restrict__ csr,
                                              const float* __restrict__ att,
                                              const float* __restrict__ bias,
                                              float* __restrict__ out) {
    int node = blockIdx.x * 4 + (threadIdx.x >> 6);
    if (node >= N_NODES) return;
    int lane = threadIdx.x & 63;
    float a = att[lane];
    size_t nb = (size_t)node * 64;
    float xrv = xr[nb + lane];
    float slv = xl[nb + lane];
    float p = lrelu(slv + xrv) * a;
    dred1(p);
    float w = __expf(rl63(p));
    float den = w;
    float acc = w * slv;

    int beg = rowptr[node], end = rowptr[node + 1];
    int cnt = end - beg;
    int quads = cnt >> 2;
    if (quads > 0) {
        const int* cp = csr + beg;
        int i0 = cp[0], i1 = cp[1], i2 = cp[2], i3 = cp[3];
        float A = xl[(size_t)i0 * 64 + lane];
        float B = xl[(size_t)i1 * 64 + lane];
        float C = xl[(size_t)i2 * 64 + lane];
        float D = xl[(size_t)i3 * 64 + lane];
        for (int q = 1; q <= quads; ++q) {
            float nA = 0.f, nB = 0.f, nC = 0.f, nD = 0.f;
            if (q < quads) {
                int j0 = cp[4 * q], j1 = cp[4 * q + 1], j2 = cp[4 * q + 2], j3 = cp[4 * q + 3];
                nA = xl[(size_t)j0 * 64 + lane];
                nB = xl[(size_t)j1 * 64 + lane];
                nC = xl[(size_t)j2 * 64 + lane];
                nD = xl[(size_t)j3 * 64 + lane];
            }
            float pa = lrelu(A + xrv) * a;
            float pb = lrelu(B + xrv) * a;
            float pc = lrelu(C + xrv) * a;
            float pd = lrelu(D + xrv) * a;
            dred4(pa, pb, pc, pd);
            float ea = __expf(rl63(pa)), eb = __expf(rl63(pb));
            float ec = __expf(rl63(pc)), ed = __expf(rl63(pd));
            den += (ea + eb) + (ec + ed);
            acc = fmaf(ea, A, fmaf(eb, B, fmaf(ec, C, fmaf(ed, D, acc))));
            A = nA; B = nB; C = nC; D = nD;
        }
    }
    int rem = cnt & 3;
    if (rem) {
        int j0 = csr[end - rem];
        int j1 = (rem > 1) ? csr[end - rem + 1] : j0;
        int j2 = (rem > 2) ? csr[end - rem + 2] : j0;
        float A = xl[(size_t)j0 * 64 + lane];
        float B = xl[(size_t)j1 * 64 + lane];
        float C = xl[(size_t)j2 * 64 + lane];
        float pa = lrelu(A + xrv) * a;
        float pb = lrelu(B + xrv) * a;
        float pc = lrelu(C + xrv) * a;
        float pd = 0.f;
        dred4(pa, pb, pc, pd);
        float ea = __expf(rl63(pa));
        float eb = (rem > 1) ? __expf(rl63(pb)) : 0.f;
        float ec = (rem > 2) ? __expf(rl63(pc)) : 0.f;
        den += ea + eb + ec;
        acc = fmaf(ea, A, fmaf(eb, B, fmaf(ec, C, acc)));
    }
    float o = acc / den + bias[lane];
    out[nb + lane] = o > 0.f ? o : expm1f(o);
}

// ---------- classifier head ----------
__global__ __launch_bounds__(256) void k_head(const float* __restrict__ H,
                                              const float* __restrict__ Wc,
                                              const float* __restrict__ bc,
                                              float* __restrict__ out) {
    __shared__ float Ws[NCLS * 64];
    __shared__ float bs[NCLS];
    for (int i = threadIdx.x; i < NCLS * 64; i += 256) Ws[i] = Wc[i];
    if (threadIdx.x < NCLS) bs[threadIdx.x] = bc[threadIdx.x];
    __syncthreads();
    int n = blockIdx.x * 256 + threadIdx.x;
    if (n >= N_NODES) return;
    const float4* hp = (const float4*)(H + (size_t)n * 64);
    float acc[NCLS] = {};
#pragma unroll
    for (int k4 = 0; k4 < 16; ++k4) {
        float4 hv = hp[k4];
#pragma unroll
        for (int c = 0; c < NCLS; ++c) {
            acc[c] = fmaf(hv.x, Ws[c * 64 + k4 * 4 + 0], acc[c]);
            acc[c] = fmaf(hv.y, Ws[c * 64 + k4 * 4 + 1], acc[c]);
            acc[c] = fmaf(hv.z, Ws[c * 64 + k4 * 4 + 2], acc[c]);
            acc[c] = fmaf(hv.w, Ws[c * 64 + k4 * 4 + 3], acc[c]);
        }
    }
#pragma unroll
    for (int c = 0; c < NCLS; ++c) out[(size_t)n * NCLS + c] = acc[c] + bs[c];
}

// ---------- launch ----------
extern "C" void kernel_launch(void* const* d_in, const int* in_sizes, int n_in,
                              void* d_out, int out_size, void* d_ws, size_t ws_size,
                              hipStream_t stream) {
    const float* x     = (const float*)d_in[0];
    const int*   ei    = (const int*)d_in[1];
    const int*   srcp  = ei;
    const int*   dstp  = ei + E_EDGES;
    const float* Wl1   = (const float*)d_in[3];
    const float* bl1   = (const float*)d_in[4];
    const float* Wr1   = (const float*)d_in[5];
    const float* br1   = (const float*)d_in[6];
    const float* att1  = (const float*)d_in[7];
    const float* bias1 = (const float*)d_in[8];
    const float* Wl2   = (const float*)d_in[9];
    const float* bl2   = (const float*)d_in[10];
    const float* Wr2   = (const float*)d_in[11];
    const float* br2   = (const float*)d_in[12];
    const float* att2  = (const float*)d_in[13];
    const float* bias2 = (const float*)d_in[14];
    const float* Wc    = (const float*)d_in[15];
    const float* bc    = (const float*)d_in[16];

    float* fA = (float*)d_ws;                       // xl1 [N,128] -> xl2 [N,64]
    float* fB = fA + (size_t)N_NODES * 128;         // xr1 [N,128] -> xr2 [N,64]
    float* fC = fB + (size_t)N_NODES * 128;         // h1  [N,128] -> h2  [N,64]
    int* rowptr = (int*)(fC + (size_t)N_NODES * 128);
    int* degcur = rowptr + (N_NODES + 1);
    int* csr    = degcur + N_NODES;
    // 16B-aligned bf16 weight splits after csr
    size_t woff = ((size_t)(csr + E_EDGES) - (size_t)d_ws + 15) & ~(size_t)15;
    short* whiL = (short*)((char*)d_ws + woff);     // 16384 each
    short* wloL = whiL + 16384;
    short* whiR = wloL + 16384;
    short* wloR = whiR + 16384;
    int* incl = (int*)(wloR + 16384);               // N ints
    int* bsum = incl + N_NODES;                     // SCAN_BLOCKS ints

    hipMemsetAsync(degcur, 0, N_NODES * sizeof(int), stream);
    k_count<<<(E_EDGES + 255) / 256, 256, 0, stream>>>(dstp, degcur);
    k_scanA<<<SCAN_BLOCKS, 256, 0, stream>>>(degcur, incl, bsum);
    k_scanB<<<1, 256, 0, stream>>>(bsum);
    k_scanC<<<SCAN_BLOCKS, 256, 0, stream>>>(degcur, incl, bsum, rowptr);
    k_scatter<<<(E_EDGES + 255) / 256, 256, 0, stream>>>(srcp, dstp, degcur, csr);

    int gblocks = (N_NODES + 63) / 64;

    // conv1: split weights, MFMA dual GEMM, gat
    k_splitW<<<64, 256, 0, stream>>>(Wl1, 16384, whiL, wloL);
    k_splitW<<<64, 256, 0, stream>>>(Wr1, 16384, whiR, wloR);
    k_mgemm<8><<<gblocks, 256, 0, stream>>>(x, whiL, wloL, whiR, wloR, bl1, br1, fA, fB, N_NODES);
    k_gat1<<<(N_NODES + 3) / 4, 256, 0, stream>>>(fA, fB, rowptr, csr, att1, bias1, fC);

    // conv2
    k_splitW<<<32, 256, 0, stream>>>(Wl2, 8192, whiL, wloL);
    k_splitW<<<32, 256, 0, stream>>>(Wr2, 8192, whiR, wloR);
    k_mgemm<4><<<gblocks, 256, 0, stream>>>(fC, whiL, wloL, whiR, wloR, bl2, br2, fA, fB, N_NODES);
    k_gat2<<<(N_NODES + 3) / 4, 256, 0, stream>>>(fA, fB, rowptr, csr, att2, bias2, fC);

    k_head<<<(N_NODES + 255) / 256, 256, 0, stream>>>(fC, Wc, bc, (float*)d_out);
}

// Round 9
// 430.613 us; speedup vs baseline: 1.6401x; 1.0280x over previous
//
#include <hip/hip_runtime.h>
#include <hip/hip_bf16.h>

#define N_NODES 50000
#define E_EDGES 800000
#define NCLS 10
#define SCAN_BLOCKS 196   // 196*256 = 50176 >= N_NODES

typedef short bfrag __attribute__((ext_vector_type(8)));   // 8 bf16 in 4 VGPRs
typedef float f32x4 __attribute__((ext_vector_type(4)));

__device__ __forceinline__ int rfl(int v) { return __builtin_amdgcn_readfirstlane(v); }

// ---------- bf16 split helpers ----------
__device__ __forceinline__ unsigned short bf16rne(float x) {
    unsigned u = __float_as_uint(x);
    unsigned r = u + 0x7FFFu + ((u >> 16) & 1u);
    return (unsigned short)(r >> 16);
}

// ---------- DPP wave-64 sum reduction ----------
template <int CTRL, int RM>
__device__ __forceinline__ float dppadd(float x) {
    int s = __builtin_amdgcn_update_dpp(0, __float_as_int(x), CTRL, RM, 0xf, true);
    return x + __int_as_float(s);
}
__device__ __forceinline__ float rl63(float x) {
    return __int_as_float(__builtin_amdgcn_readlane(__float_as_int(x), 63));
}
__device__ __forceinline__ void dred1(float& x0) {
    x0 = dppadd<0x111, 0xf>(x0);
    x0 = dppadd<0x112, 0xf>(x0);
    x0 = dppadd<0x114, 0xf>(x0);
    x0 = dppadd<0x118, 0xf>(x0);
    x0 = dppadd<0x142, 0xa>(x0);
    x0 = dppadd<0x143, 0xc>(x0);
}
__device__ __forceinline__ void dred2(float& x0, float& x1) {
    x0 = dppadd<0x111, 0xf>(x0); x1 = dppadd<0x111, 0xf>(x1);
    x0 = dppadd<0x112, 0xf>(x0); x1 = dppadd<0x112, 0xf>(x1);
    x0 = dppadd<0x114, 0xf>(x0); x1 = dppadd<0x114, 0xf>(x1);
    x0 = dppadd<0x118, 0xf>(x0); x1 = dppadd<0x118, 0xf>(x1);
    x0 = dppadd<0x142, 0xa>(x0); x1 = dppadd<0x142, 0xa>(x1);
    x0 = dppadd<0x143, 0xc>(x0); x1 = dppadd<0x143, 0xc>(x1);
}
__device__ __forceinline__ void dred4(float& x0, float& x1, float& x2, float& x3) {
    x0 = dppadd<0x111, 0xf>(x0); x1 = dppadd<0x111, 0xf>(x1);
    x2 = dppadd<0x111, 0xf>(x2); x3 = dppadd<0x111, 0xf>(x3);
    x0 = dppadd<0x112, 0xf>(x0); x1 = dppadd<0x112, 0xf>(x1);
    x2 = dppadd<0x112, 0xf>(x2); x3 = dppadd<0x112, 0xf>(x3);
    x0 = dppadd<0x114, 0xf>(x0); x1 = dppadd<0x114, 0xf>(x1);
    x2 = dppadd<0x114, 0xf>(x2); x3 = dppadd<0x114, 0xf>(x3);
    x0 = dppadd<0x118, 0xf>(x0); x1 = dppadd<0x118, 0xf>(x1);
    x2 = dppadd<0x118, 0xf>(x2); x3 = dppadd<0x118, 0xf>(x3);
    x0 = dppadd<0x142, 0xa>(x0); x1 = dppadd<0x142, 0xa>(x1);
    x2 = dppadd<0x142, 0xa>(x2); x3 = dppadd<0x142, 0xa>(x3);
    x0 = dppadd<0x143, 0xc>(x0); x1 = dppadd<0x143, 0xc>(x1);
    x2 = dppadd<0x143, 0xc>(x2); x3 = dppadd<0x143, 0xc>(x3);
}
__device__ __forceinline__ float lrelu(float u) { return u > 0.f ? u : 0.2f * u; }

// ---------- CSR build ----------
__global__ void k_count(const int* __restrict__ dst, int* __restrict__ deg) {
    int i = blockIdx.x * blockDim.x + threadIdx.x;
    if (i < E_EDGES) {
        unsigned d = (unsigned)dst[i];
        if (d < N_NODES) atomicAdd(&deg[d], 1);
    }
}

// hierarchical exclusive scan, 3 passes, all parallel
__global__ void k_scanA(const int* __restrict__ deg, int* __restrict__ incl,
                        int* __restrict__ bsum) {
    __shared__ int s[256];
    int i = blockIdx.x * 256 + threadIdx.x;
    int v = (i < N_NODES) ? deg[i] : 0;
    s[threadIdx.x] = v;
    __syncthreads();
    for (int off = 1; off < 256; off <<= 1) {
        int t = (threadIdx.x >= off) ? s[threadIdx.x - off] : 0;
        __syncthreads();
        s[threadIdx.x] += t;
        __syncthreads();
    }
    if (i < N_NODES) incl[i] = s[threadIdx.x];
    if (threadIdx.x == 255) bsum[blockIdx.x] = s[255];
}

__global__ void k_scanB(int* __restrict__ bsum) {
    __shared__ int s[256];
    int t = threadIdx.x;
    s[t] = (t < SCAN_BLOCKS) ? bsum[t] : 0;
    __syncthreads();
    for (int off = 1; off < 256; off <<= 1) {
        int v = (t >= off) ? s[t - off] : 0;
        __syncthreads();
        s[t] += v;
        __syncthreads();
    }
    if (t < SCAN_BLOCKS) bsum[t] = s[t];  // inclusive block sums
}

__global__ void k_scanC(int* __restrict__ degcur, const int* __restrict__ incl,
                        const int* __restrict__ bsum, int* __restrict__ rowptr) {
    int i = blockIdx.x * 256 + threadIdx.x;
    if (i >= N_NODES) return;
    int base = (blockIdx.x == 0) ? 0 : bsum[blockIdx.x - 1];
    int d = degcur[i];
    int excl = base + incl[i] - d;
    rowptr[i] = excl;
    degcur[i] = excl;  // cursor init
    if (i == N_NODES - 1) rowptr[N_NODES] = base + incl[i];
}

__global__ void k_scatter(const int* __restrict__ src, const int* __restrict__ dst,
                          int* __restrict__ cursor, int* __restrict__ csr_src) {
    int i = blockIdx.x * blockDim.x + threadIdx.x;
    if (i < E_EDGES) {
        unsigned d = (unsigned)dst[i];
        if (d < N_NODES) {
            int p = atomicAdd(&cursor[d], 1);
            unsigned s = (unsigned)src[i];
            csr_src[p] = (s < N_NODES) ? (int)s : 0;
        }
    }
}

// ---------- split fp32 weight -> hi/lo bf16 ----------
__global__ void k_splitW(const float* __restrict__ W, int n,
                         short* __restrict__ hi, short* __restrict__ lo) {
    int i = blockIdx.x * 256 + threadIdx.x;
    if (i < n) {
        float x = W[i];
        unsigned short h = bf16rne(x);
        float hf = __uint_as_float((unsigned)h << 16);
        unsigned short l = bf16rne(x - hf);
        hi[i] = (short)h;
        lo[i] = (short)l;
    }
}

// ---------- MFMA dual GEMM (split-bf16 fp32 emulation) ----------
template <int NCT>
__global__ __launch_bounds__(256) void k_mgemm(const float* __restrict__ X,
                                               const short* __restrict__ whl,
                                               const short* __restrict__ wll,
                                               const short* __restrict__ whr,
                                               const short* __restrict__ wlr,
                                               const float* __restrict__ bl,
                                               const float* __restrict__ br,
                                               float* __restrict__ Yl,
                                               float* __restrict__ Yr, int nrows) {
    const int NOUT = NCT * 16;
    int tid = threadIdx.x;
    int wv = tid >> 6, lane = tid & 63;
    int m = lane & 15, g = lane >> 4;
    int row = blockIdx.x * 64 + wv * 16 + m;
    int rowc = min(row, nrows - 1);

    bfrag ahi[4], alo[4];
    const float* xp = X + (size_t)rowc * 128 + g * 8;
#pragma unroll
    for (int kb = 0; kb < 4; ++kb) {
        float4 u0 = *(const float4*)(xp + kb * 32);
        float4 u1 = *(const float4*)(xp + kb * 32 + 4);
        float xs[8] = {u0.x, u0.y, u0.z, u0.w, u1.x, u1.y, u1.z, u1.w};
#pragma unroll
        for (int j = 0; j < 8; ++j) {
            unsigned short h = bf16rne(xs[j]);
            float hf = __uint_as_float((unsigned)h << 16);
            unsigned short l = bf16rne(xs[j] - hf);
            ahi[kb][j] = (short)h;
            alo[kb][j] = (short)l;
        }
    }

    f32x4 accl[NCT], accr[NCT];
#pragma unroll
    for (int ct = 0; ct < NCT; ++ct) {
        accl[ct] = (f32x4){0.f, 0.f, 0.f, 0.f};
        accr[ct] = (f32x4){0.f, 0.f, 0.f, 0.f};
    }

#pragma unroll
    for (int kb = 0; kb < 4; ++kb) {
#pragma unroll
        for (int ct = 0; ct < NCT; ++ct) {
            size_t wo = (size_t)(ct * 16 + m) * 128 + kb * 32 + g * 8;
            bfrag bhl = *(const bfrag*)(whl + wo);
            bfrag bll = *(const bfrag*)(wll + wo);
            bfrag bhr = *(const bfrag*)(whr + wo);
            bfrag blr = *(const bfrag*)(wlr + wo);
            accl[ct] = __builtin_amdgcn_mfma_f32_16x16x32_bf16(ahi[kb], bhl, accl[ct], 0, 0, 0);
            accl[ct] = __builtin_amdgcn_mfma_f32_16x16x32_bf16(alo[kb], bhl, accl[ct], 0, 0, 0);
            accl[ct] = __builtin_amdgcn_mfma_f32_16x16x32_bf16(ahi[kb], bll, accl[ct], 0, 0, 0);
            accr[ct] = __builtin_amdgcn_mfma_f32_16x16x32_bf16(ahi[kb], bhr, accr[ct], 0, 0, 0);
            accr[ct] = __builtin_amdgcn_mfma_f32_16x16x32_bf16(alo[kb], bhr, accr[ct], 0, 0, 0);
            accr[ct] = __builtin_amdgcn_mfma_f32_16x16x32_bf16(ahi[kb], blr, accr[ct], 0, 0, 0);
        }
    }

    int orow0 = blockIdx.x * 64 + wv * 16 + g * 4;
#pragma unroll
    for (int ct = 0; ct < NCT; ++ct) {
        int col = ct * 16 + m;
        float blv = bl[col], brv = br[col];
#pragma unroll
        for (int i = 0; i < 4; ++i) {
            int orow = orow0 + i;
            if (orow < nrows) {
                Yl[(size_t)orow * NOUT + col] = accl[ct][i] + blv;
                Yr[(size_t)orow * NOUT + col] = accr[ct][i] + brv;
            }
        }
    }
}

// ---------- GATv2 layer 1: H=2, C=64, concat -> out[N][128], fused bias+ELU ----------
// node & neighbor indices forced to SGPR via readfirstlane: CSR reads become
// s_loads, gather addrs become SGPR-base + lane voffset (no per-lane 64b math).
__global__ __launch_bounds__(256) void k_gat1(const float* __restrict__ xl,
                                              const float* __restrict__ xr,
                                              const int* __restrict__ rowptr,
                                              const int* __restrict__ csr,
                                              const float* __restrict__ att,
                                              const float* __restrict__ bias,
                                              float* __restrict__ out) {
    int node = blockIdx.x * 4 + (threadIdx.x >> 6);
    if (node >= N_NODES) return;
    node = rfl(node);
    int lane = threadIdx.x & 63;
    float a0 = att[lane], a1 = att[64 + lane];
    size_t nb = (size_t)node << 7;
    float xr0 = xr[nb + lane], xr1 = xr[nb + 64 + lane];
    float sl0 = xl[nb + lane], sl1 = xl[nb + 64 + lane];
    float p0 = lrelu(sl0 + xr0) * a0;
    float p1 = lrelu(sl1 + xr1) * a1;
    dred2(p0, p1);
    float w0 = __expf(rl63(p0)), w1 = __expf(rl63(p1));
    float den0 = w0, den1 = w1;
    float acc0 = w0 * sl0, acc1 = w1 * sl1;

    int beg = rfl(rowptr[node]), end = rfl(rowptr[node + 1]);
    int cnt = end - beg;
    int npairs = cnt >> 1;
    if (npairs > 0) {
        const int* cp = csr + beg;
        int i0 = rfl(cp[0]), i1 = rfl(cp[1]);
        const float* rA = xl + ((size_t)(unsigned)i0 << 7);
        const float* rB = xl + ((size_t)(unsigned)i1 << 7);
        float A0 = rA[lane], A1 = rA[lane + 64];
        float B0 = rB[lane], B1 = rB[lane + 64];
        for (int p = 1; p <= npairs; ++p) {
            float nA0 = 0.f, nA1 = 0.f, nB0 = 0.f, nB1 = 0.f;
            if (p < npairs) {
                int j0 = rfl(cp[2 * p]), j1 = rfl(cp[2 * p + 1]);
                const float* sA = xl + ((size_t)(unsigned)j0 << 7);
                const float* sB = xl + ((size_t)(unsigned)j1 << 7);
                nA0 = sA[lane]; nA1 = sA[lane + 64];
                nB0 = sB[lane]; nB1 = sB[lane + 64];
            }
            float pa0 = lrelu(A0 + xr0) * a0;
            float pa1 = lrelu(A1 + xr1) * a1;
            float pb0 = lrelu(B0 + xr0) * a0;
            float pb1 = lrelu(B1 + xr1) * a1;
            dred4(pa0, pa1, pb0, pb1);
            float ea0 = __expf(rl63(pa0)), ea1 = __expf(rl63(pa1));
            float eb0 = __expf(rl63(pb0)), eb1 = __expf(rl63(pb1));
            den0 += ea0 + eb0;
            den1 += ea1 + eb1;
            acc0 = fmaf(ea0, A0, fmaf(eb0, B0, acc0));
            acc1 = fmaf(ea1, A1, fmaf(eb1, B1, acc1));
            A0 = nA0; A1 = nA1; B0 = nB0; B1 = nB1;
        }
    }
    if (cnt & 1) {
        int j = rfl(csr[end - 1]);
        const float* rC = xl + ((size_t)(unsigned)j << 7);
        float C0 = rC[lane], C1 = rC[lane + 64];
        float q0 = lrelu(C0 + xr0) * a0;
        float q1 = lrelu(C1 + xr1) * a1;
        dred2(q0, q1);
        float e0 = __expf(rl63(q0)), e1 = __expf(rl63(q1));
        den0 += e0; den1 += e1;
        acc0 = fmaf(e0, C0, acc0);
        acc1 = fmaf(e1, C1, acc1);
    }
    float o0 = acc0 / den0 + bias[lane];
    float o1 = acc1 / den1 + bias[64 + lane];
    out[nb + lane] = o0 > 0.f ? o0 : expm1f(o0);
    out[nb + 64 + lane] = o1 > 0.f ? o1 : expm1f(o1);
}

// ---------- GATv2 layer 2: H=1, C=64 -> out[N][64], fused bias+ELU ----------
__global__ __launch_bounds__(256) void k_gat2(const float* __restrict__ xl,
                                              const float* __restrict__ xr,
                                              const int* __restrict__ rowptr,
                                              const int* __restrict__ csr,
                                              const float* __restrict__ att,
                                              const float* __restrict__ bias,
                                              float* __restrict__ out) {
    int node = blockIdx.x * 4 + (threadIdx.x >> 6);
    if (node >= N_NODES) return;
    node = rfl(node);
    int lane = threadIdx.x & 63;
    float a = att[lane];
    size_t nb = (size_t)node << 6;
    float xrv = xr[nb + lane];
    float slv = xl[nb + lane];
    float p = lrelu(slv + xrv) * a;
    dred1(p);
    float w = __expf(rl63(p));
    float den = w;
    float acc = w * slv;

    int beg = rfl(rowptr[node]), end = rfl(rowptr[node + 1]);
    int cnt = end - beg;
    int quads = cnt >> 2;
    if (quads > 0) {
        const int* cp = csr + beg;
        int i0 = rfl(cp[0]), i1 = rfl(cp[1]), i2 = rfl(cp[2]), i3 = rfl(cp[3]);
        float A = (xl + ((size_t)(unsigned)i0 << 6))[lane];
        float B = (xl + ((size_t)(unsigned)i1 << 6))[lane];
        float C = (xl + ((size_t)(unsigned)i2 << 6))[lane];
        float D = (xl + ((size_t)(unsigned)i3 << 6))[lane];
        for (int q = 1; q <= quads; ++q) {
            float nA = 0.f, nB = 0.f, nC = 0.f, nD = 0.f;
            if (q < quads) {
                int j0 = rfl(cp[4 * q]), j1 = rfl(cp[4 * q + 1]);
                int j2 = rfl(cp[4 * q + 2]), j3 = rfl(cp[4 * q + 3]);
                nA = (xl + ((size_t)(unsigned)j0 << 6))[lane];
                nB = (xl + ((size_t)(unsigned)j1 << 6))[lane];
                nC = (xl + ((size_t)(unsigned)j2 << 6))[lane];
                nD = (xl + ((size_t)(unsigned)j3 << 6))[lane];
            }
            float pa = lrelu(A + xrv) * a;
            float pb = lrelu(B + xrv) * a;
            float pc = lrelu(C + xrv) * a;
            float pd = lrelu(D + xrv) * a;
            dred4(pa, pb, pc, pd);
            float ea = __expf(rl63(pa)), eb = __expf(rl63(pb));
            float ec = __expf(rl63(pc)), ed = __expf(rl63(pd));
            den += (ea + eb) + (ec + ed);
            acc = fmaf(ea, A, fmaf(eb, B, fmaf(ec, C, fmaf(ed, D, acc))));
            A = nA; B = nB; C = nC; D = nD;
        }
    }
    int rem = cnt & 3;
    if (rem) {
        int j0 = rfl(csr[end - rem]);
        int j1 = (rem > 1) ? rfl(csr[end - rem + 1]) : j0;
        int j2 = (rem > 2) ? rfl(csr[end - rem + 2]) : j0;
        float A = (xl + ((size_t)(unsigned)j0 << 6))[lane];
        float B = (xl + ((size_t)(unsigned)j1 << 6))[lane];
        float C = (xl + ((size_t)(unsigned)j2 << 6))[lane];
        float pa = lrelu(A + xrv) * a;
        float pb = lrelu(B + xrv) * a;
        float pc = lrelu(C + xrv) * a;
        float pd = 0.f;
        dred4(pa, pb, pc, pd);
        float ea = __expf(rl63(pa));
        float eb = (rem > 1) ? __expf(rl63(pb)) : 0.f;
        float ec = (rem > 2) ? __expf(rl63(pc)) : 0.f;
        den += ea + eb + ec;
        acc = fmaf(ea, A, fmaf(eb, B, fmaf(ec, C, acc)));
    }
    float o = acc / den + bias[lane];
    out[nb + lane] = o > 0.f ? o : expm1f(o);
}

// ---------- classifier head ----------
__global__ __launch_bounds__(256) void k_head(const float* __restrict__ H,
                                              const float* __restrict__ Wc,
                                              const float* __restrict__ bc,
                                              float* __restrict__ out) {
    __shared__ float Ws[NCLS * 64];
    __shared__ float bs[NCLS];
    for (int i = threadIdx.x; i < NCLS * 64; i += 256) Ws[i] = Wc[i];
    if (threadIdx.x < NCLS) bs[threadIdx.x] = bc[threadIdx.x];
    __syncthreads();
    int n = blockIdx.x * 256 + threadIdx.x;
    if (n >= N_NODES) return;
    const float4* hp = (const float4*)(H + (size_t)n * 64);
    float acc[NCLS] = {};
#pragma unroll
    for (int k4 = 0; k4 < 16; ++k4) {
        float4 hv = hp[k4];
#pragma unroll
        for (int c = 0; c < NCLS; ++c) {
            acc[c] = fmaf(hv.x, Ws[c * 64 + k4 * 4 + 0], acc[c]);
            acc[c] = fmaf(hv.y, Ws[c * 64 + k4 * 4 + 1], acc[c]);
            acc[c] = fmaf(hv.z, Ws[c * 64 + k4 * 4 + 2], acc[c]);
            acc[c] = fmaf(hv.w, Ws[c * 64 + k4 * 4 + 3], acc[c]);
        }
    }
#pragma unroll
    for (int c = 0; c < NCLS; ++c) out[(size_t)n * NCLS + c] = acc[c] + bs[c];
}

// ---------- launch ----------
extern "C" void kernel_launch(void* const* d_in, const int* in_sizes, int n_in,
                              void* d_out, int out_size, void* d_ws, size_t ws_size,
                              hipStream_t stream) {
    const float* x     = (const float*)d_in[0];
    const int*   ei    = (const int*)d_in[1];
    const int*   srcp  = ei;
    const int*   dstp  = ei + E_EDGES;
    const float* Wl1   = (const float*)d_in[3];
    const float* bl1   = (const float*)d_in[4];
    const float* Wr1   = (const float*)d_in[5];
    const float* br1   = (const float*)d_in[6];
    const float* att1  = (const float*)d_in[7];
    const float* bias1 = (const float*)d_in[8];
    const float* Wl2   = (const float*)d_in[9];
    const float* bl2   = (const float*)d_in[10];
    const float* Wr2   = (const float*)d_in[11];
    const float* br2   = (const float*)d_in[12];
    const float* att2  = (const float*)d_in[13];
    const float* bias2 = (const float*)d_in[14];
    const float* Wc    = (const float*)d_in[15];
    const float* bc    = (const float*)d_in[16];

    float* fA = (float*)d_ws;                       // xl1 [N,128] -> xl2 [N,64]
    float* fB = fA + (size_t)N_NODES * 128;         // xr1 [N,128] -> xr2 [N,64]
    float* fC = fB + (size_t)N_NODES * 128;         // h1  [N,128] -> h2  [N,64]
    int* rowptr = (int*)(fC + (size_t)N_NODES * 128);
    int* degcur = rowptr + (N_NODES + 1);
    int* csr    = degcur + N_NODES;
    // 16B-aligned bf16 weight splits after csr
    size_t woff = ((size_t)(csr + E_EDGES) - (size_t)d_ws + 15) & ~(size_t)15;
    short* whiL = (short*)((char*)d_ws + woff);     // 16384 each
    short* wloL = whiL + 16384;
    short* whiR = wloL + 16384;
    short* wloR = whiR + 16384;
    int* incl = (int*)(wloR + 16384);               // N ints
    int* bsum = incl + N_NODES;                     // SCAN_BLOCKS ints

    hipMemsetAsync(degcur, 0, N_NODES * sizeof(int), stream);
    k_count<<<(E_EDGES + 255) / 256, 256, 0, stream>>>(dstp, degcur);
    k_scanA<<<SCAN_BLOCKS, 256, 0, stream>>>(degcur, incl, bsum);
    k_scanB<<<1, 256, 0, stream>>>(bsum);
    k_scanC<<<SCAN_BLOCKS, 256, 0, stream>>>(degcur, incl, bsum, rowptr);
    k_scatter<<<(E_EDGES + 255) / 256, 256, 0, stream>>>(srcp, dstp, degcur, csr);

    int gblocks = (N_NODES + 63) / 64;

    // conv1: split weights, MFMA dual GEMM, gat
    k_splitW<<<64, 256, 0, stream>>>(Wl1, 16384, whiL, wloL);
    k_splitW<<<64, 256, 0, stream>>>(Wr1, 16384, whiR, wloR);
    k_mgemm<8><<<gblocks, 256, 0, stream>>>(x, whiL, wloL, whiR, wloR, bl1, br1, fA, fB, N_NODES);
    k_gat1<<<(N_NODES + 3) / 4, 256, 0, stream>>>(fA, fB, rowptr, csr, att1, bias1, fC);

    // conv2
    k_splitW<<<32, 256, 0, stream>>>(Wl2, 8192, whiL, wloL);
    k_splitW<<<32, 256, 0, stream>>>(Wr2, 8192, whiR, wloR);
    k_mgemm<4><<<gblocks, 256, 0, stream>>>(fC, whiL, wloL, whiR, wloR, bl2, br2, fA, fB, N_NODES);
    k_gat2<<<(N_NODES + 3) / 4, 256, 0, stream>>>(fA, fB, rowptr, csr, att2, bias2, fC);

    k_head<<<(N_NODES + 255) / 256, 256, 0, stream>>>(fC, Wc, bc, (float*)d_out);
}

// Round 10
// 425.191 us; speedup vs baseline: 1.6610x; 1.0128x over previous
//
#include <hip/hip_runtime.h>
#include <hip/hip_bf16.h>

#define N_NODES 50000
#define E_EDGES 800000
#define NCLS 10
#define SCAN_BLOCKS 196   // 196*256 = 50176 >= N_NODES

typedef short bfrag __attribute__((ext_vector_type(8)));   // 8 bf16 in 4 VGPRs
typedef float f32x4 __attribute__((ext_vector_type(4)));

__device__ __forceinline__ int rfl(int v) { return __builtin_amdgcn_readfirstlane(v); }

// ---------- bf16 split helpers ----------
__device__ __forceinline__ unsigned short bf16rne(float x) {
    unsigned u = __float_as_uint(x);
    unsigned r = u + 0x7FFFu + ((u >> 16) & 1u);
    return (unsigned short)(r >> 16);
}

// ---------- DPP wave-64 sum reductions ----------
template <int CTRL, int RM>
__device__ __forceinline__ float dppadd(float x) {
    int s = __builtin_amdgcn_update_dpp(0, __float_as_int(x), CTRL, RM, 0xf, true);
    return x + __int_as_float(s);
}
__device__ __forceinline__ float rl63(float x) {
    return __int_as_float(__builtin_amdgcn_readlane(__float_as_int(x), 63));
}
__device__ __forceinline__ float rl31(float x) {
    return __int_as_float(__builtin_amdgcn_readlane(__float_as_int(x), 31));
}
// full 64-lane reduce (total in lane 63): 6 stages
__device__ __forceinline__ void dred1(float& x0) {
    x0 = dppadd<0x111, 0xf>(x0);
    x0 = dppadd<0x112, 0xf>(x0);
    x0 = dppadd<0x114, 0xf>(x0);
    x0 = dppadd<0x118, 0xf>(x0);
    x0 = dppadd<0x142, 0xa>(x0);
    x0 = dppadd<0x143, 0xc>(x0);
}
__device__ __forceinline__ void dred4(float& x0, float& x1, float& x2, float& x3) {
    x0 = dppadd<0x111, 0xf>(x0); x1 = dppadd<0x111, 0xf>(x1);
    x2 = dppadd<0x111, 0xf>(x2); x3 = dppadd<0x111, 0xf>(x3);
    x0 = dppadd<0x112, 0xf>(x0); x1 = dppadd<0x112, 0xf>(x1);
    x2 = dppadd<0x112, 0xf>(x2); x3 = dppadd<0x112, 0xf>(x3);
    x0 = dppadd<0x114, 0xf>(x0); x1 = dppadd<0x114, 0xf>(x1);
    x2 = dppadd<0x114, 0xf>(x2); x3 = dppadd<0x114, 0xf>(x3);
    x0 = dppadd<0x118, 0xf>(x0); x1 = dppadd<0x118, 0xf>(x1);
    x2 = dppadd<0x118, 0xf>(x2); x3 = dppadd<0x118, 0xf>(x3);
    x0 = dppadd<0x142, 0xa>(x0); x1 = dppadd<0x142, 0xa>(x1);
    x2 = dppadd<0x142, 0xa>(x2); x3 = dppadd<0x142, 0xa>(x3);
    x0 = dppadd<0x143, 0xc>(x0); x1 = dppadd<0x143, 0xc>(x1);
    x2 = dppadd<0x143, 0xc>(x2); x3 = dppadd<0x143, 0xc>(x3);
}
// half-wave reduce, 5 stages: lane31 = sum(lanes 0-31), lane63 = sum(lanes 32-63)
__device__ __forceinline__ void dredH(float& x) {
    x = dppadd<0x111, 0xf>(x);
    x = dppadd<0x112, 0xf>(x);
    x = dppadd<0x114, 0xf>(x);
    x = dppadd<0x118, 0xf>(x);
    x = dppadd<0x142, 0xa>(x);
}
__device__ __forceinline__ void dredH2(float& x, float& y) {
    x = dppadd<0x111, 0xf>(x); y = dppadd<0x111, 0xf>(y);
    x = dppadd<0x112, 0xf>(x); y = dppadd<0x112, 0xf>(y);
    x = dppadd<0x114, 0xf>(x); y = dppadd<0x114, 0xf>(y);
    x = dppadd<0x118, 0xf>(x); y = dppadd<0x118, 0xf>(y);
    x = dppadd<0x142, 0xa>(x); y = dppadd<0x142, 0xa>(y);
}
__device__ __forceinline__ float lrelu(float u) { return u > 0.f ? u : 0.2f * u; }
// packed edge score partial: sum over 2 packed comps of lrelu(v+xr)*a
__device__ __forceinline__ float escore(float2 v, float2 xr2, float2 av) {
    float ux = v.x + xr2.x, uy = v.y + xr2.y;
    ux = fmaxf(ux, 0.2f * ux);
    uy = fmaxf(uy, 0.2f * uy);
    return ux * av.x + uy * av.y;
}

// ---------- CSR build ----------
__global__ void k_count(const int* __restrict__ dst, int* __restrict__ deg) {
    int i = blockIdx.x * blockDim.x + threadIdx.x;
    if (i < E_EDGES) {
        unsigned d = (unsigned)dst[i];
        if (d < N_NODES) atomicAdd(&deg[d], 1);
    }
}

// hierarchical exclusive scan, 3 passes, all parallel
__global__ void k_scanA(const int* __restrict__ deg, int* __restrict__ incl,
                        int* __restrict__ bsum) {
    __shared__ int s[256];
    int i = blockIdx.x * 256 + threadIdx.x;
    int v = (i < N_NODES) ? deg[i] : 0;
    s[threadIdx.x] = v;
    __syncthreads();
    for (int off = 1; off < 256; off <<= 1) {
        int t = (threadIdx.x >= off) ? s[threadIdx.x - off] : 0;
        __syncthreads();
        s[threadIdx.x] += t;
        __syncthreads();
    }
    if (i < N_NODES) incl[i] = s[threadIdx.x];
    if (threadIdx.x == 255) bsum[blockIdx.x] = s[255];
}

__global__ void k_scanB(int* __restrict__ bsum) {
    __shared__ int s[256];
    int t = threadIdx.x;
    s[t] = (t < SCAN_BLOCKS) ? bsum[t] : 0;
    __syncthreads();
    for (int off = 1; off < 256; off <<= 1) {
        int v = (t >= off) ? s[t - off] : 0;
        __syncthreads();
        s[t] += v;
        __syncthreads();
    }
    if (t < SCAN_BLOCKS) bsum[t] = s[t];  // inclusive block sums
}

__global__ void k_scanC(int* __restrict__ degcur, const int* __restrict__ incl,
                        const int* __restrict__ bsum, int* __restrict__ rowptr) {
    int i = blockIdx.x * 256 + threadIdx.x;
    if (i >= N_NODES) return;
    int base = (blockIdx.x == 0) ? 0 : bsum[blockIdx.x - 1];
    int d = degcur[i];
    int excl = base + incl[i] - d;
    rowptr[i] = excl;
    degcur[i] = excl;  // cursor init
    if (i == N_NODES - 1) rowptr[N_NODES] = base + incl[i];
}

__global__ void k_scatter(const int* __restrict__ src, const int* __restrict__ dst,
                          int* __restrict__ cursor, int* __restrict__ csr_src) {
    int i = blockIdx.x * blockDim.x + threadIdx.x;
    if (i < E_EDGES) {
        unsigned d = (unsigned)dst[i];
        if (d < N_NODES) {
            int p = atomicAdd(&cursor[d], 1);
            unsigned s = (unsigned)src[i];
            csr_src[p] = (s < N_NODES) ? (int)s : 0;
        }
    }
}

// ---------- split fp32 weight -> hi/lo bf16 ----------
__global__ void k_splitW(const float* __restrict__ W, int n,
                         short* __restrict__ hi, short* __restrict__ lo) {
    int i = blockIdx.x * 256 + threadIdx.x;
    if (i < n) {
        float x = W[i];
        unsigned short h = bf16rne(x);
        float hf = __uint_as_float((unsigned)h << 16);
        unsigned short l = bf16rne(x - hf);
        hi[i] = (short)h;
        lo[i] = (short)l;
    }
}

// ---------- MFMA dual GEMM (split-bf16 fp32 emulation) ----------
template <int NCT>
__global__ __launch_bounds__(256) void k_mgemm(const float* __restrict__ X,
                                               const short* __restrict__ whl,
                                               const short* __restrict__ wll,
                                               const short* __restrict__ whr,
                                               const short* __restrict__ wlr,
                                               const float* __restrict__ bl,
                                               const float* __restrict__ br,
                                               float* __restrict__ Yl,
                                               float* __restrict__ Yr, int nrows) {
    const int NOUT = NCT * 16;
    int tid = threadIdx.x;
    int wv = tid >> 6, lane = tid & 63;
    int m = lane & 15, g = lane >> 4;
    int row = blockIdx.x * 64 + wv * 16 + m;
    int rowc = min(row, nrows - 1);

    bfrag ahi[4], alo[4];
    const float* xp = X + (size_t)rowc * 128 + g * 8;
#pragma unroll
    for (int kb = 0; kb < 4; ++kb) {
        float4 u0 = *(const float4*)(xp + kb * 32);
        float4 u1 = *(const float4*)(xp + kb * 32 + 4);
        float xs[8] = {u0.x, u0.y, u0.z, u0.w, u1.x, u1.y, u1.z, u1.w};
#pragma unroll
        for (int j = 0; j < 8; ++j) {
            unsigned short h = bf16rne(xs[j]);
            float hf = __uint_as_float((unsigned)h << 16);
            unsigned short l = bf16rne(xs[j] - hf);
            ahi[kb][j] = (short)h;
            alo[kb][j] = (short)l;
        }
    }

    f32x4 accl[NCT], accr[NCT];
#pragma unroll
    for (int ct = 0; ct < NCT; ++ct) {
        accl[ct] = (f32x4){0.f, 0.f, 0.f, 0.f};
        accr[ct] = (f32x4){0.f, 0.f, 0.f, 0.f};
    }

#pragma unroll
    for (int kb = 0; kb < 4; ++kb) {
#pragma unroll
        for (int ct = 0; ct < NCT; ++ct) {
            size_t wo = (size_t)(ct * 16 + m) * 128 + kb * 32 + g * 8;
            bfrag bhl = *(const bfrag*)(whl + wo);
            bfrag bll = *(const bfrag*)(wll + wo);
            bfrag bhr = *(const bfrag*)(whr + wo);
            bfrag blr = *(const bfrag*)(wlr + wo);
            accl[ct] = __builtin_amdgcn_mfma_f32_16x16x32_bf16(ahi[kb], bhl, accl[ct], 0, 0, 0);
            accl[ct] = __builtin_amdgcn_mfma_f32_16x16x32_bf16(alo[kb], bhl, accl[ct], 0, 0, 0);
            accl[ct] = __builtin_amdgcn_mfma_f32_16x16x32_bf16(ahi[kb], bll, accl[ct], 0, 0, 0);
            accr[ct] = __builtin_amdgcn_mfma_f32_16x16x32_bf16(ahi[kb], bhr, accr[ct], 0, 0, 0);
            accr[ct] = __builtin_amdgcn_mfma_f32_16x16x32_bf16(alo[kb], bhr, accr[ct], 0, 0, 0);
            accr[ct] = __builtin_amdgcn_mfma_f32_16x16x32_bf16(ahi[kb], blr, accr[ct], 0, 0, 0);
        }
    }

    int orow0 = blockIdx.x * 64 + wv * 16 + g * 4;
#pragma unroll
    for (int ct = 0; ct < NCT; ++ct) {
        int col = ct * 16 + m;
        float blv = bl[col], brv = br[col];
#pragma unroll
        for (int i = 0; i < 4; ++i) {
            int orow = orow0 + i;
            if (orow < nrows) {
                Yl[(size_t)orow * NOUT + col] = accl[ct][i] + blv;
                Yr[(size_t)orow * NOUT + col] = accr[ct][i] + brv;
            }
        }
    }
}

// ---------- GATv2 layer 1: H=2, C=64, concat -> out[N][128], fused bias+ELU ----------
// float2-packed: lane l holds elems (2l,2l+1); lanes 0-31 = head0, 32-63 = head1.
// One 5-stage DPP reduce yields head0 score in lane31, head1 in lane63.
__global__ __launch_bounds__(256) void k_gat1(const float* __restrict__ xl,
                                              const float* __restrict__ xr,
                                              const int* __restrict__ rowptr,
                                              const int* __restrict__ csr,
                                              const float* __restrict__ att,
                                              const float* __restrict__ bias,
                                              float* __restrict__ out) {
    int node = blockIdx.x * 4 + (threadIdx.x >> 6);
    if (node >= N_NODES) return;
    node = rfl(node);
    int lane = threadIdx.x & 63;
    bool lo = lane < 32;
    const float2* xl2 = (const float2*)xl;
    size_t nb = (size_t)node * 64;   // row offset in float2 units (128 floats)
    float2 av = ((const float2*)att)[lane];
    float2 xr2 = ((const float2*)xr)[nb + lane];
    float2 sl2 = xl2[nb + lane];

    // self loop
    float p = escore(sl2, xr2, av);
    dredH(p);
    float e0 = __expf(rl31(p)), e1 = __expf(rl63(p));
    float ev = lo ? e0 : e1;
    float den = ev;
    float2 acc;
    acc.x = ev * sl2.x;
    acc.y = ev * sl2.y;

    int beg = rfl(rowptr[node]), end = rfl(rowptr[node + 1]);
    int cnt = end - beg;
    int np = cnt >> 1;
    if (np > 0) {
        const int* cp = csr + beg;
        int i0 = rfl(cp[0]), i1 = rfl(cp[1]);
        float2 A = xl2[(size_t)(unsigned)i0 * 64 + lane];
        float2 B = xl2[(size_t)(unsigned)i1 * 64 + lane];
        for (int q = 1; q <= np; ++q) {
            float2 nA = {0.f, 0.f}, nB = {0.f, 0.f};
            if (q < np) {
                int j0 = rfl(cp[2 * q]), j1 = rfl(cp[2 * q + 1]);
                nA = xl2[(size_t)(unsigned)j0 * 64 + lane];
                nB = xl2[(size_t)(unsigned)j1 * 64 + lane];
            }
            float pa = escore(A, xr2, av);
            float pb = escore(B, xr2, av);
            dredH2(pa, pb);
            float ea0 = __expf(rl31(pa)), ea1 = __expf(rl63(pa));
            float eb0 = __expf(rl31(pb)), eb1 = __expf(rl63(pb));
            float eva = lo ? ea0 : ea1;
            float evb = lo ? eb0 : eb1;
            den += eva + evb;
            acc.x = fmaf(eva, A.x, fmaf(evb, B.x, acc.x));
            acc.y = fmaf(eva, A.y, fmaf(evb, B.y, acc.y));
            A = nA; B = nB;
        }
    }
    if (cnt & 1) {
        int j = rfl(csr[end - 1]);
        float2 C = xl2[(size_t)(unsigned)j * 64 + lane];
        float pc = escore(C, xr2, av);
        dredH(pc);
        float ec0 = __expf(rl31(pc)), ec1 = __expf(rl63(pc));
        float evc = lo ? ec0 : ec1;
        den += evc;
        acc.x = fmaf(evc, C.x, acc.x);
        acc.y = fmaf(evc, C.y, acc.y);
    }
    float2 b2 = ((const float2*)bias)[lane];
    float ox = acc.x / den + b2.x;
    float oy = acc.y / den + b2.y;
    ox = ox > 0.f ? ox : expm1f(ox);
    oy = oy > 0.f ? oy : expm1f(oy);
    float2 o2 = {ox, oy};
    ((float2*)out)[nb + lane] = o2;
}

// ---------- GATv2 layer 2: H=1, C=64 -> out[N][64], fused bias+ELU ----------
__global__ __launch_bounds__(256) void k_gat2(const float* __restrict__ xl,
                                              const float* __restrict__ xr,
                                              const int* __restrict__ rowptr,
                                              const int* __restrict__ csr,
                                              const float* __restrict__ att,
                                              const float* __restrict__ bias,
                                              float* __restrict__ out) {
    int node = blockIdx.x * 4 + (threadIdx.x >> 6);
    if (node >= N_NODES) return;
    node = rfl(node);
    int lane = threadIdx.x & 63;
    float a = att[lane];
    size_t nb = (size_t)node << 6;
    float xrv = xr[nb + lane];
    float slv = xl[nb + lane];
    float p = lrelu(slv + xrv) * a;
    dred1(p);
    float w = __expf(rl63(p));
    float den = w;
    float acc = w * slv;

    int beg = rfl(rowptr[node]), end = rfl(rowptr[node + 1]);
    int cnt = end - beg;
    int quads = cnt >> 2;
    if (quads > 0) {
        const int* cp = csr + beg;
        int i0 = rfl(cp[0]), i1 = rfl(cp[1]), i2 = rfl(cp[2]), i3 = rfl(cp[3]);
        float A = (xl + ((size_t)(unsigned)i0 << 6))[lane];
        float B = (xl + ((size_t)(unsigned)i1 << 6))[lane];
        float C = (xl + ((size_t)(unsigned)i2 << 6))[lane];
        float D = (xl + ((size_t)(unsigned)i3 << 6))[lane];
        for (int q = 1; q <= quads; ++q) {
            float nA = 0.f, nB = 0.f, nC = 0.f, nD = 0.f;
            if (q < quads) {
                int j0 = rfl(cp[4 * q]), j1 = rfl(cp[4 * q + 1]);
                int j2 = rfl(cp[4 * q + 2]), j3 = rfl(cp[4 * q + 3]);
                nA = (xl + ((size_t)(unsigned)j0 << 6))[lane];
                nB = (xl + ((size_t)(unsigned)j1 << 6))[lane];
                nC = (xl + ((size_t)(unsigned)j2 << 6))[lane];
                nD = (xl + ((size_t)(unsigned)j3 << 6))[lane];
            }
            float pa = lrelu(A + xrv) * a;
            float pb = lrelu(B + xrv) * a;
            float pc = lrelu(C + xrv) * a;
            float pd = lrelu(D + xrv) * a;
            dred4(pa, pb, pc, pd);
            float ea = __expf(rl63(pa)), eb = __expf(rl63(pb));
            float ec = __expf(rl63(pc)), ed = __expf(rl63(pd));
            den += (ea + eb) + (ec + ed);
            acc = fmaf(ea, A, fmaf(eb, B, fmaf(ec, C, fmaf(ed, D, acc))));
            A = nA; B = nB; C = nC; D = nD;
        }
    }
    int rem = cnt & 3;
    if (rem) {
        int j0 = rfl(csr[end - rem]);
        int j1 = (rem > 1) ? rfl(csr[end - rem + 1]) : j0;
        int j2 = (rem > 2) ? rfl(csr[end - rem + 2]) : j0;
        float A = (xl + ((size_t)(unsigned)j0 << 6))[lane];
        float B = (xl + ((size_t)(unsigned)j1 << 6))[lane];
        float C = (xl + ((size_t)(unsigned)j2 << 6))[lane];
        float pa = lrelu(A + xrv) * a;
        float pb = lrelu(B + xrv) * a;
        float pc = lrelu(C + xrv) * a;
        float pd = 0.f;
        dred4(pa, pb, pc, pd);
        float ea = __expf(rl63(pa));
        float eb = (rem > 1) ? __expf(rl63(pb)) : 0.f;
        float ec = (rem > 2) ? __expf(rl63(pc)) : 0.f;
        den += ea + eb + ec;
        acc = fmaf(ea, A, fmaf(eb, B, fmaf(ec, C, acc)));
    }
    float o = acc / den + bias[lane];
    out[nb + lane] = o > 0.f ? o : expm1f(o);
}

// ---------- classifier head ----------
__global__ __launch_bounds__(256) void k_head(const float* __restrict__ H,
                                              const float* __restrict__ Wc,
                                              const float* __restrict__ bc,
                                              float* __restrict__ out) {
    __shared__ float Ws[NCLS * 64];
    __shared__ float bs[NCLS];
    for (int i = threadIdx.x; i < NCLS * 64; i += 256) Ws[i] = Wc[i];
    if (threadIdx.x < NCLS) bs[threadIdx.x] = bc[threadIdx.x];
    __syncthreads();
    int n = blockIdx.x * 256 + threadIdx.x;
    if (n >= N_NODES) return;
    const float4* hp = (const float4*)(H + (size_t)n * 64);
    float acc[NCLS] = {};
#pragma unroll
    for (int k4 = 0; k4 < 16; ++k4) {
        float4 hv = hp[k4];
#pragma unroll
        for (int c = 0; c < NCLS; ++c) {
            acc[c] = fmaf(hv.x, Ws[c * 64 + k4 * 4 + 0], acc[c]);
            acc[c] = fmaf(hv.y, Ws[c * 64 + k4 * 4 + 1], acc[c]);
            acc[c] = fmaf(hv.z, Ws[c * 64 + k4 * 4 + 2], acc[c]);
            acc[c] = fmaf(hv.w, Ws[c * 64 + k4 * 4 + 3], acc[c]);
        }
    }
#pragma unroll
    for (int c = 0; c < NCLS; ++c) out[(size_t)n * NCLS + c] = acc[c] + bs[c];
}

// ---------- launch ----------
extern "C" void kernel_launch(void* const* d_in, const int* in_sizes, int n_in,
                              void* d_out, int out_size, void* d_ws, size_t ws_size,
                              hipStream_t stream) {
    const float* x     = (const float*)d_in[0];
    const int*   ei    = (const int*)d_in[1];
    const int*   srcp  = ei;
    const int*   dstp  = ei + E_EDGES;
    const float* Wl1   = (const float*)d_in[3];
    const float* bl1   = (const float*)d_in[4];
    const float* Wr1   = (const float*)d_in[5];
    const float* br1   = (const float*)d_in[6];
    const float* att1  = (const float*)d_in[7];
    const float* bias1 = (const float*)d_in[8];
    const float* Wl2   = (const float*)d_in[9];
    const float* bl2   = (const float*)d_in[10];
    const float* Wr2   = (const float*)d_in[11];
    const float* br2   = (const float*)d_in[12];
    const float* att2  = (const float*)d_in[13];
    const float* bias2 = (const float*)d_in[14];
    const float* Wc    = (const float*)d_in[15];
    const float* bc    = (const float*)d_in[16];

    float* fA = (float*)d_ws;                       // xl1 [N,128] -> xl2 [N,64]
    float* fB = fA + (size_t)N_NODES * 128;         // xr1 [N,128] -> xr2 [N,64]
    float* fC = fB + (size_t)N_NODES * 128;         // h1  [N,128] -> h2  [N,64]
    int* rowptr = (int*)(fC + (size_t)N_NODES * 128);
    int* degcur = rowptr + (N_NODES + 1);
    int* csr    = degcur + N_NODES;
    // 16B-aligned bf16 weight splits after csr
    size_t woff = ((size_t)(csr + E_EDGES) - (size_t)d_ws + 15) & ~(size_t)15;
    short* whiL = (short*)((char*)d_ws + woff);     // 16384 each
    short* wloL = whiL + 16384;
    short* whiR = wloL + 16384;
    short* wloR = whiR + 16384;
    int* incl = (int*)(wloR + 16384);               // N ints
    int* bsum = incl + N_NODES;                     // SCAN_BLOCKS ints

    hipMemsetAsync(degcur, 0, N_NODES * sizeof(int), stream);
    k_count<<<(E_EDGES + 255) / 256, 256, 0, stream>>>(dstp, degcur);
    k_scanA<<<SCAN_BLOCKS, 256, 0, stream>>>(degcur, incl, bsum);
    k_scanB<<<1, 256, 0, stream>>>(bsum);
    k_scanC<<<SCAN_BLOCKS, 256, 0, stream>>>(degcur, incl, bsum, rowptr);
    k_scatter<<<(E_EDGES + 255) / 256, 256, 0, stream>>>(srcp, dstp, degcur, csr);

    int gblocks = (N_NODES + 63) / 64;

    // conv1: split weights, MFMA dual GEMM, gat
    k_splitW<<<64, 256, 0, stream>>>(Wl1, 16384, whiL, wloL);
    k_splitW<<<64, 256, 0, stream>>>(Wr1, 16384, whiR, wloR);
    k_mgemm<8><<<gblocks, 256, 0, stream>>>(x, whiL, wloL, whiR, wloR, bl1, br1, fA, fB, N_NODES);
    k_gat1<<<(N_NODES + 3) / 4, 256, 0, stream>>>(fA, fB, rowptr, csr, att1, bias1, fC);

    // conv2
    k_splitW<<<32, 256, 0, stream>>>(Wl2, 8192, whiL, wloL);
    k_splitW<<<32, 256, 0, stream>>>(Wr2, 8192, whiR, wloR);
    k_mgemm<4><<<gblocks, 256, 0, stream>>>(fC, whiL, wloL, whiR, wloR, bl2, br2, fA, fB, N_NODES);
    k_gat2<<<(N_NODES + 3) / 4, 256, 0, stream>>>(fA, fB, rowptr, csr, att2, bias2, fC);

    k_head<<<(N_NODES + 255) / 256, 256, 0, stream>>>(fC, Wc, bc, (float*)d_out);
}